// Round 2
// baseline (2350.321 us; speedup 1.0000x reference)
//
#include <hip/hip_runtime.h>

// Problem constants
constexpr int Bn = 2;
constexpr int Sn = 2048;
constexpr int En = 512;
constexpr int Hn = 8;
constexpr int Dn = 64;
constexpr int Mn = Bn * Sn;              // 4096 rows
constexpr int PLANE = Bn * Hn * Sn * Dn; // 2,097,152 elements per q/k/v plane

// ---------------------------------------------------------------------------
// Kernel 1: fused QKV projection. A = x (4096 x 512), B = [Wq|Wk|Wv] per-head
// (512 x 1536). Output q,k,v planes fp32, layout [(b*H+h)*S + s]*D + d.
// 64x64 tile, BK=16, 256 threads, 4x4 per thread.
// ---------------------------------------------------------------------------
__global__ __launch_bounds__(256)
void qkv_gemm(const float* __restrict__ x,
              const float* __restrict__ Wq,
              const float* __restrict__ Wk,
              const float* __restrict__ Wv,
              float* __restrict__ qkv)
{
    __shared__ float As[16][65];
    __shared__ float Bs[16][65];
    const int m0 = blockIdx.x * 64;
    const int n0 = blockIdx.y * 64;   // multiple of 64 -> single (proj, head)
    const int tid = threadIdx.x;
    const int ty = tid >> 4, tx = tid & 15;

    const int proj = n0 >> 9;         // 0=q 1=k 2=v
    const int r = n0 & 511;
    const int h = r >> 6;
    const float* W = (proj == 0) ? Wq : (proj == 1) ? Wk : Wv;
    const float* Wh = W + (size_t)h * En * Dn;

    const int arow = tid >> 2;            // 0..63
    const int acol = (tid & 3) * 4;       // 0..12
    const int brow = tid >> 4;            // k 0..15
    const int bcol = (tid & 15) * 4;      // d 0..60

    float acc[4][4] = {};

    for (int k0 = 0; k0 < En; k0 += 16) {
        float4 av = *(const float4*)(x + (size_t)(m0 + arow) * En + k0 + acol);
        float4 bv = *(const float4*)(Wh + (size_t)(k0 + brow) * Dn + bcol);
        As[acol + 0][arow] = av.x;
        As[acol + 1][arow] = av.y;
        As[acol + 2][arow] = av.z;
        As[acol + 3][arow] = av.w;
        Bs[brow][bcol + 0] = bv.x;
        Bs[brow][bcol + 1] = bv.y;
        Bs[brow][bcol + 2] = bv.z;
        Bs[brow][bcol + 3] = bv.w;
        __syncthreads();
        #pragma unroll
        for (int kk = 0; kk < 16; ++kk) {
            float a[4], b[4];
            #pragma unroll
            for (int i = 0; i < 4; ++i) a[i] = As[kk][ty * 4 + i];
            #pragma unroll
            for (int j = 0; j < 4; ++j) b[j] = Bs[kk][tx * 4 + j];
            #pragma unroll
            for (int i = 0; i < 4; ++i)
                #pragma unroll
                for (int j = 0; j < 4; ++j) acc[i][j] += a[i] * b[j];
        }
        __syncthreads();
    }

    float* base = qkv + (size_t)proj * PLANE;
    #pragma unroll
    for (int i = 0; i < 4; ++i) {
        const int m = m0 + ty * 4 + i;
        const int b = m >> 11;            // /2048
        const int s = m & 2047;
        float* dst = base + (((size_t)(b * Hn + h) * Sn + s) * Dn);
        #pragma unroll
        for (int j = 0; j < 4; ++j) {
            dst[tx * 4 + j] = acc[i][j];
        }
    }
}

// ---------------------------------------------------------------------------
// Kernel 2: causal flash attention. One 64-thread block per (b,h,qtile of 64).
// Thread = one q row; q/o/p in registers; K/V tiles staged in LDS (reads are
// wave-uniform -> broadcast, conflict-free). Online softmax. Head-reversed
// write into vals[b,s,(7-h)*64+d]. No 1/sqrt(d) scale (per reference).
// ---------------------------------------------------------------------------
__global__ __launch_bounds__(64)
void attn(const float* __restrict__ qkv, float* __restrict__ vals)
{
    __shared__ float kt[64][64];
    __shared__ float vt[64][64];

    const int bid = blockIdx.x;
    const int qt = bid & 31;
    const int bh = bid >> 5;              // b*8+h
    const int b = bh >> 3, h = bh & 7;
    const int tid = threadIdx.x;
    const int s = qt * 64 + tid;

    const float* qp = qkv + ((size_t)bh * Sn + s) * Dn;
    const float* kbase = qkv + (size_t)PLANE + (size_t)bh * Sn * Dn;
    const float* vbase = qkv + (size_t)2 * PLANE + (size_t)bh * Sn * Dn;

    float q[64], o[64];
    #pragma unroll
    for (int d = 0; d < 64; ++d) { q[d] = qp[d]; o[d] = 0.f; }
    float m = -INFINITY, l = 0.f;

    const int ntiles = qt + 1;
    for (int it = 0; it < ntiles; ++it) {
        const int t0 = it * 64;
        __syncthreads();
        for (int idx = tid; idx < 1024; idx += 64) {
            const int row = idx >> 4;
            const int c4 = idx & 15;
            ((float4*)&kt[row][0])[c4] = ((const float4*)(kbase + (size_t)(t0 + row) * 64))[c4];
            ((float4*)&vt[row][0])[c4] = ((const float4*)(vbase + (size_t)(t0 + row) * 64))[c4];
        }
        __syncthreads();

        float p[64];
        float mt = -INFINITY;
        #pragma unroll
        for (int t = 0; t < 64; ++t) {
            float dot = 0.f;
            #pragma unroll
            for (int d4 = 0; d4 < 16; ++d4) {
                float4 kv = ((const float4*)&kt[t][0])[d4];
                dot += q[d4 * 4 + 0] * kv.x + q[d4 * 4 + 1] * kv.y +
                       q[d4 * 4 + 2] * kv.z + q[d4 * 4 + 3] * kv.w;
            }
            p[t] = ((t0 + t) <= s) ? dot : -INFINITY;
            mt = fmaxf(mt, p[t]);
        }
        const float mnew = fmaxf(m, mt);          // always finite (diag in tile 0)
        const float alpha = __expf(m - mnew);     // exp(-inf)=0 on first tile
        l *= alpha;
        #pragma unroll
        for (int d = 0; d < 64; ++d) o[d] *= alpha;
        #pragma unroll
        for (int t = 0; t < 64; ++t) {
            const float w = __expf(p[t] - mnew);  // masked -> exp(-inf)=0
            p[t] = w;
            l += w;
        }
        #pragma unroll
        for (int t = 0; t < 64; ++t) {
            const float w = p[t];
            #pragma unroll
            for (int d4 = 0; d4 < 16; ++d4) {
                float4 vv = ((const float4*)&vt[t][0])[d4];
                o[d4 * 4 + 0] += w * vv.x;
                o[d4 * 4 + 1] += w * vv.y;
                o[d4 * 4 + 2] += w * vv.z;
                o[d4 * 4 + 3] += w * vv.w;
            }
        }
        m = mnew;
    }

    const float inv = 1.f / l;
    float* dst = vals + ((size_t)(b * Sn + s)) * En + (size_t)(7 - h) * 64;
    #pragma unroll
    for (int d = 0; d < 64; ++d) dst[d] = o[d] * inv;
}

// ---------------------------------------------------------------------------
// Kernel 3: out = vals @ Wp^T + bp + x  (pre-LN, fp32 out). 64x64 tiles.
// B[k][n] = Wp[n][k] (contraction over Wp's 2nd axis).
// ---------------------------------------------------------------------------
__global__ __launch_bounds__(256)
void out_gemm(const float* __restrict__ vals,
              const float* __restrict__ Wp,
              const float* __restrict__ bp,
              const float* __restrict__ x,
              float* __restrict__ outp)
{
    __shared__ float As[16][65];
    __shared__ float Bs[16][65];
    const int m0 = blockIdx.x * 64;
    const int n0 = blockIdx.y * 64;
    const int tid = threadIdx.x;
    const int ty = tid >> 4, tx = tid & 15;

    const int arow = tid >> 2;
    const int acol = (tid & 3) * 4;
    const int bn = tid >> 2;              // n 0..63
    const int bk = (tid & 3) * 4;         // k 0..12

    float acc[4][4] = {};

    for (int k0 = 0; k0 < En; k0 += 16) {
        float4 av = *(const float4*)(vals + (size_t)(m0 + arow) * En + k0 + acol);
        float4 wv = *(const float4*)(Wp + (size_t)(n0 + bn) * En + k0 + bk);
        As[acol + 0][arow] = av.x;
        As[acol + 1][arow] = av.y;
        As[acol + 2][arow] = av.z;
        As[acol + 3][arow] = av.w;
        Bs[bk + 0][bn] = wv.x;
        Bs[bk + 1][bn] = wv.y;
        Bs[bk + 2][bn] = wv.z;
        Bs[bk + 3][bn] = wv.w;
        __syncthreads();
        #pragma unroll
        for (int kk = 0; kk < 16; ++kk) {
            float a[4], b[4];
            #pragma unroll
            for (int i = 0; i < 4; ++i) a[i] = As[kk][ty * 4 + i];
            #pragma unroll
            for (int j = 0; j < 4; ++j) b[j] = Bs[kk][tx * 4 + j];
            #pragma unroll
            for (int i = 0; i < 4; ++i)
                #pragma unroll
                for (int j = 0; j < 4; ++j) acc[i][j] += a[i] * b[j];
        }
        __syncthreads();
    }

    #pragma unroll
    for (int i = 0; i < 4; ++i) {
        const int m = m0 + ty * 4 + i;
        #pragma unroll
        for (int j = 0; j < 4; ++j) {
            const int n = n0 + tx * 4 + j;
            const size_t idx = (size_t)m * En + n;
            outp[idx] = acc[i][j] + bp[n] + x[idx];
        }
    }
}

// ---------------------------------------------------------------------------
// Kernel 4: row-wise LayerNorm (E=512), fp32 in, fp32 out.
// ---------------------------------------------------------------------------
__global__ __launch_bounds__(256)
void ln_kernel(const float* __restrict__ outp,
               const float* __restrict__ gamma,
               const float* __restrict__ beta,
               float* __restrict__ y)
{
    const int row = blockIdx.x;
    const int tid = threadIdx.x;
    const float* r = outp + (size_t)row * En;

    const float a = r[tid];
    const float b = r[tid + 256];
    float sum = a + b;
    float sq = a * a + b * b;
    #pragma unroll
    for (int off = 32; off > 0; off >>= 1) {
        sum += __shfl_down(sum, off);
        sq  += __shfl_down(sq, off);
    }
    __shared__ float ls[4], lq[4];
    const int wid = tid >> 6, lane = tid & 63;
    if (lane == 0) { ls[wid] = sum; lq[wid] = sq; }
    __syncthreads();
    if (tid == 0) {
        float S = 0.f, Q = 0.f;
        #pragma unroll
        for (int w = 0; w < 4; ++w) { S += ls[w]; Q += lq[w]; }
        ls[0] = S; lq[0] = Q;
    }
    __syncthreads();
    const float mu = ls[0] * (1.f / 512.f);
    const float var = lq[0] * (1.f / 512.f) - mu * mu;
    const float rs = rsqrtf(var + 1e-5f);

    float* yr = y + (size_t)row * En;
    yr[tid]       = (a - mu) * rs * gamma[tid]       + beta[tid];
    yr[tid + 256] = (b - mu) * rs * gamma[tid + 256] + beta[tid + 256];
}

// ---------------------------------------------------------------------------
extern "C" void kernel_launch(void* const* d_in, const int* in_sizes, int n_in,
                              void* d_out, int out_size, void* d_ws, size_t ws_size,
                              hipStream_t stream)
{
    const float* x     = (const float*)d_in[0];
    const float* Wq    = (const float*)d_in[1];
    const float* Wk    = (const float*)d_in[2];
    const float* Wv    = (const float*)d_in[3];
    const float* Wp    = (const float*)d_in[4];
    const float* bp    = (const float*)d_in[5];
    const float* gamma = (const float*)d_in[6];
    const float* beta  = (const float*)d_in[7];
    // d_in[8] = mask (int32 tril) — causal, applied analytically.

    float* ws   = (float*)d_ws;
    float* qkv  = ws;                        // 3 * PLANE floats (24 MB)
    float* vals = ws + (size_t)3 * PLANE;    // Mn*En floats (8 MB)
    float* outp = vals + (size_t)Mn * En;    // Mn*En floats (8 MB)

    qkv_gemm<<<dim3(Mn / 64, (3 * En) / 64), 256, 0, stream>>>(x, Wq, Wk, Wv, qkv);
    attn<<<dim3(Bn * Hn * (Sn / 64)), 64, 0, stream>>>(qkv, vals);
    out_gemm<<<dim3(Mn / 64, En / 64), 256, 0, stream>>>(vals, Wp, bp, x, outp);
    ln_kernel<<<dim3(Mn), 256, 0, stream>>>(outp, gamma, beta, (float*)d_out);
}

// Round 3
// 476.726 us; speedup vs baseline: 4.9301x; 4.9301x over previous
//
#include <hip/hip_runtime.h>

// Problem constants
constexpr int Bn = 2;
constexpr int Sn = 2048;
constexpr int En = 512;
constexpr int Hn = 8;
constexpr int Dn = 64;
constexpr int Mn = Bn * Sn;              // 4096 rows
constexpr int PLANE = Bn * Hn * Sn * Dn; // 2,097,152 elements per q/k/v plane

// ---------------------------------------------------------------------------
// Kernel 1: fused QKV projection (unchanged from R2).
// ---------------------------------------------------------------------------
__global__ __launch_bounds__(256)
void qkv_gemm(const float* __restrict__ x,
              const float* __restrict__ Wq,
              const float* __restrict__ Wk,
              const float* __restrict__ Wv,
              float* __restrict__ qkv)
{
    __shared__ float As[16][65];
    __shared__ float Bs[16][65];
    const int m0 = blockIdx.x * 64;
    const int n0 = blockIdx.y * 64;
    const int tid = threadIdx.x;
    const int ty = tid >> 4, tx = tid & 15;

    const int proj = n0 >> 9;
    const int r = n0 & 511;
    const int h = r >> 6;
    const float* W = (proj == 0) ? Wq : (proj == 1) ? Wk : Wv;
    const float* Wh = W + (size_t)h * En * Dn;

    const int arow = tid >> 2;
    const int acol = (tid & 3) * 4;
    const int brow = tid >> 4;
    const int bcol = (tid & 15) * 4;

    float acc[4][4] = {};

    for (int k0 = 0; k0 < En; k0 += 16) {
        float4 av = *(const float4*)(x + (size_t)(m0 + arow) * En + k0 + acol);
        float4 bv = *(const float4*)(Wh + (size_t)(k0 + brow) * Dn + bcol);
        As[acol + 0][arow] = av.x;
        As[acol + 1][arow] = av.y;
        As[acol + 2][arow] = av.z;
        As[acol + 3][arow] = av.w;
        Bs[brow][bcol + 0] = bv.x;
        Bs[brow][bcol + 1] = bv.y;
        Bs[brow][bcol + 2] = bv.z;
        Bs[brow][bcol + 3] = bv.w;
        __syncthreads();
        #pragma unroll
        for (int kk = 0; kk < 16; ++kk) {
            float a[4], b[4];
            #pragma unroll
            for (int i = 0; i < 4; ++i) a[i] = As[kk][ty * 4 + i];
            #pragma unroll
            for (int j = 0; j < 4; ++j) b[j] = Bs[kk][tx * 4 + j];
            #pragma unroll
            for (int i = 0; i < 4; ++i)
                #pragma unroll
                for (int j = 0; j < 4; ++j) acc[i][j] += a[i] * b[j];
        }
        __syncthreads();
    }

    float* base = qkv + (size_t)proj * PLANE;
    #pragma unroll
    for (int i = 0; i < 4; ++i) {
        const int m = m0 + ty * 4 + i;
        const int b = m >> 11;
        const int s = m & 2047;
        float* dst = base + (((size_t)(b * Hn + h) * Sn + s) * Dn);
        #pragma unroll
        for (int j = 0; j < 4; ++j) {
            dst[tx * 4 + j] = acc[i][j];
        }
    }
}

// ---------------------------------------------------------------------------
// Kernel 2 (v2): block-level flash attention.
// 256 threads per (b,h,64-row Q-tile). Per 64-wide K-tile:
//   A: S = Q K^T  (64x64x64 mini-GEMM, 4x4/thread, LDS d-major Q/K)
//   B: online softmax (4 threads/row, shfl_xor across sub-lanes)
//   C: O = O*alpha + W V (64x64x64 mini-GEMM, o[4][4] in registers)
// LDS: qt[d][r] 64x64, kt[d][t] 64x64, vt[t][d] 64x68, st[r][t] 64x68
//      + alf[64] + linv[64]  = 68,096 B dynamic shared.
// ---------------------------------------------------------------------------
__global__ __launch_bounds__(256)
void attn(const float* __restrict__ qkv, float* __restrict__ vals)
{
    extern __shared__ float smem[];
    float (*qt_s)[64] = (float(*)[64])(smem);                 // [d][r]
    float (*kt_s)[64] = (float(*)[64])(smem + 4096);          // [d][t]
    float (*vt_s)[68] = (float(*)[68])(smem + 8192);          // [t][d]
    float (*st_s)[68] = (float(*)[68])(smem + 8192 + 4352);   // [r][t]
    float* alf_s  = smem + 8192 + 8704;                       // [64]
    float* linv_s = alf_s + 64;                               // [64]

    const int bidx = blockIdx.x;
    const int jj_ = bidx >> 4;
    const int bh = bidx & 15;
    const int qt = (jj_ < 16) ? jj_ : 47 - jj_;   // complementary pairing for balance
    const int b = bh >> 3, h = bh & 7;
    const int tid = threadIdx.x;
    const int ty = tid >> 4, tx = tid & 15;
    const int ty4 = ty * 4, tx4 = tx * 4;

    const float* qg = qkv + ((size_t)bh * Sn + (size_t)qt * 64) * Dn;
    const float* kg = qkv + (size_t)PLANE + (size_t)bh * Sn * Dn;
    const float* vg = qkv + (size_t)2 * PLANE + (size_t)bh * Sn * Dn;

    // Load Q tile transposed into qt_s[d][r]
    {
        const int qrow = tid >> 2, dg = tid & 3;
        #pragma unroll
        for (int c = 0; c < 4; ++c) {
            float4 v = *(const float4*)(qg + (size_t)qrow * Dn + dg * 16 + 4 * c);
            qt_s[dg * 16 + 4 * c + 0][qrow] = v.x;
            qt_s[dg * 16 + 4 * c + 1][qrow] = v.y;
            qt_s[dg * 16 + 4 * c + 2][qrow] = v.z;
            qt_s[dg * 16 + 4 * c + 3][qrow] = v.w;
        }
    }

    float o[4][4] = {};
    float m = -INFINITY, l = 0.f;
    const int r_b = tid >> 2, dg_b = tid & 3;

    const int ntk = qt + 1;
    for (int it = 0; it < ntk; ++it) {
        const int t0 = it * 64;
        __syncthreads();   // protect kt/vt/st from previous iteration's readers
        // Load K (transposed -> kt_s[d][t]) and V (natural -> vt_s[t][d])
        {
            const int trow = tid >> 2, dg = tid & 3;
            const float* kr = kg + (size_t)(t0 + trow) * Dn + dg * 16;
            const float* vr = vg + (size_t)(t0 + trow) * Dn + dg * 16;
            #pragma unroll
            for (int c = 0; c < 4; ++c) {
                float4 kv = *(const float4*)(kr + 4 * c);
                kt_s[dg * 16 + 4 * c + 0][trow] = kv.x;
                kt_s[dg * 16 + 4 * c + 1][trow] = kv.y;
                kt_s[dg * 16 + 4 * c + 2][trow] = kv.z;
                kt_s[dg * 16 + 4 * c + 3][trow] = kv.w;
                *(float4*)&vt_s[trow][dg * 16 + 4 * c] = *(const float4*)(vr + 4 * c);
            }
        }
        __syncthreads();

        // Phase A: scores (with causal mask on the diagonal tile)
        {
            float acc[4][4] = {};
            #pragma unroll 8
            for (int kk = 0; kk < 64; ++kk) {
                float4 a = *(const float4*)&qt_s[kk][ty4];
                float4 bq = *(const float4*)&kt_s[kk][tx4];
                float av[4] = {a.x, a.y, a.z, a.w};
                float bv[4] = {bq.x, bq.y, bq.z, bq.w};
                #pragma unroll
                for (int i = 0; i < 4; ++i)
                    #pragma unroll
                    for (int jx = 0; jx < 4; ++jx)
                        acc[i][jx] += av[i] * bv[jx];
            }
            const int toff = t0 - qt * 64;   // <=0; ==0 only on diagonal tile
            #pragma unroll
            for (int i = 0; i < 4; ++i) {
                float4 w;
                w.x = (tx4 + 0 + toff > ty4 + i) ? -INFINITY : acc[i][0];
                w.y = (tx4 + 1 + toff > ty4 + i) ? -INFINITY : acc[i][1];
                w.z = (tx4 + 2 + toff > ty4 + i) ? -INFINITY : acc[i][2];
                w.w = (tx4 + 3 + toff > ty4 + i) ? -INFINITY : acc[i][3];
                *(float4*)&st_s[ty4 + i][tx4] = w;
            }
        }
        __syncthreads();

        // Phase B: online softmax. Thread (r_b, dg_b) owns 16 t's of row r_b.
        {
            float sv[16];
            #pragma unroll
            for (int c = 0; c < 4; ++c) {
                float4 t4v = *(const float4*)&st_s[r_b][dg_b * 16 + 4 * c];
                sv[4 * c + 0] = t4v.x; sv[4 * c + 1] = t4v.y;
                sv[4 * c + 2] = t4v.z; sv[4 * c + 3] = t4v.w;
            }
            float mt = -INFINITY;
            #pragma unroll
            for (int u = 0; u < 16; ++u) mt = fmaxf(mt, sv[u]);
            mt = fmaxf(mt, __shfl_xor(mt, 1));
            mt = fmaxf(mt, __shfl_xor(mt, 2));
            const float mnew = fmaxf(m, mt);
            const float alpha = __expf(m - mnew);   // first tile: exp(-inf)=0
            float ls = 0.f;
            #pragma unroll
            for (int u = 0; u < 16; ++u) { sv[u] = __expf(sv[u] - mnew); ls += sv[u]; }
            ls += __shfl_xor(ls, 1);
            ls += __shfl_xor(ls, 2);
            l = l * alpha + ls;
            m = mnew;
            #pragma unroll
            for (int c = 0; c < 4; ++c) {
                float4 t4v;
                t4v.x = sv[4 * c + 0]; t4v.y = sv[4 * c + 1];
                t4v.z = sv[4 * c + 2]; t4v.w = sv[4 * c + 3];
                *(float4*)&st_s[r_b][dg_b * 16 + 4 * c] = t4v;
            }
            if (dg_b == 0) alf_s[r_b] = alpha;
        }
        __syncthreads();

        // Phase C: O = O*alpha + W V
        {
            float al[4];
            #pragma unroll
            for (int i = 0; i < 4; ++i) al[i] = alf_s[ty4 + i];
            #pragma unroll
            for (int i = 0; i < 4; ++i)
                #pragma unroll
                for (int jx = 0; jx < 4; ++jx) o[i][jx] *= al[i];
            #pragma unroll 4
            for (int t4 = 0; t4 < 64; t4 += 4) {
                float wv[4][4], vv[4][4];
                #pragma unroll
                for (int i = 0; i < 4; ++i) {
                    float4 w = *(const float4*)&st_s[ty4 + i][t4];
                    wv[i][0] = w.x; wv[i][1] = w.y; wv[i][2] = w.z; wv[i][3] = w.w;
                }
                #pragma unroll
                for (int u = 0; u < 4; ++u) {
                    float4 v = *(const float4*)&vt_s[t4 + u][tx4];
                    vv[u][0] = v.x; vv[u][1] = v.y; vv[u][2] = v.z; vv[u][3] = v.w;
                }
                #pragma unroll
                for (int u = 0; u < 4; ++u)
                    #pragma unroll
                    for (int i = 0; i < 4; ++i)
                        #pragma unroll
                        for (int jx = 0; jx < 4; ++jx)
                            o[i][jx] += wv[i][u] * vv[u][jx];
            }
        }
    }

    __syncthreads();
    if (dg_b == 0) linv_s[r_b] = 1.f / l;
    __syncthreads();

    // Epilogue: normalize + head-reversed write
    #pragma unroll
    for (int i = 0; i < 4; ++i) {
        const float li = linv_s[ty4 + i];
        float4 w;
        w.x = o[i][0] * li; w.y = o[i][1] * li;
        w.z = o[i][2] * li; w.w = o[i][3] * li;
        float* dst = vals + ((size_t)(b * Sn + qt * 64 + ty4 + i)) * En
                     + (size_t)(7 - h) * 64 + tx4;
        *(float4*)dst = w;
    }
}

// ---------------------------------------------------------------------------
// Kernel 3: out = vals @ Wp^T + bp + x (unchanged from R2).
// ---------------------------------------------------------------------------
__global__ __launch_bounds__(256)
void out_gemm(const float* __restrict__ vals,
              const float* __restrict__ Wp,
              const float* __restrict__ bp,
              const float* __restrict__ x,
              float* __restrict__ outp)
{
    __shared__ float As[16][65];
    __shared__ float Bs[16][65];
    const int m0 = blockIdx.x * 64;
    const int n0 = blockIdx.y * 64;
    const int tid = threadIdx.x;
    const int ty = tid >> 4, tx = tid & 15;

    const int arow = tid >> 2;
    const int acol = (tid & 3) * 4;
    const int bn = tid >> 2;
    const int bk = (tid & 3) * 4;

    float acc[4][4] = {};

    for (int k0 = 0; k0 < En; k0 += 16) {
        float4 av = *(const float4*)(vals + (size_t)(m0 + arow) * En + k0 + acol);
        float4 wv = *(const float4*)(Wp + (size_t)(n0 + bn) * En + k0 + bk);
        As[acol + 0][arow] = av.x;
        As[acol + 1][arow] = av.y;
        As[acol + 2][arow] = av.z;
        As[acol + 3][arow] = av.w;
        Bs[bk + 0][bn] = wv.x;
        Bs[bk + 1][bn] = wv.y;
        Bs[bk + 2][bn] = wv.z;
        Bs[bk + 3][bn] = wv.w;
        __syncthreads();
        #pragma unroll
        for (int kk = 0; kk < 16; ++kk) {
            float a[4], b[4];
            #pragma unroll
            for (int i = 0; i < 4; ++i) a[i] = As[kk][ty * 4 + i];
            #pragma unroll
            for (int j = 0; j < 4; ++j) b[j] = Bs[kk][tx * 4 + j];
            #pragma unroll
            for (int i = 0; i < 4; ++i)
                #pragma unroll
                for (int j = 0; j < 4; ++j) acc[i][j] += a[i] * b[j];
        }
        __syncthreads();
    }

    #pragma unroll
    for (int i = 0; i < 4; ++i) {
        const int mm = m0 + ty * 4 + i;
        #pragma unroll
        for (int j = 0; j < 4; ++j) {
            const int n = n0 + tx * 4 + j;
            const size_t idx = (size_t)mm * En + n;
            outp[idx] = acc[i][j] + bp[n] + x[idx];
        }
    }
}

// ---------------------------------------------------------------------------
// Kernel 4: row-wise LayerNorm (unchanged from R2).
// ---------------------------------------------------------------------------
__global__ __launch_bounds__(256)
void ln_kernel(const float* __restrict__ outp,
               const float* __restrict__ gamma,
               const float* __restrict__ beta,
               float* __restrict__ y)
{
    const int row = blockIdx.x;
    const int tid = threadIdx.x;
    const float* r = outp + (size_t)row * En;

    const float a = r[tid];
    const float b = r[tid + 256];
    float sum = a + b;
    float sq = a * a + b * b;
    #pragma unroll
    for (int off = 32; off > 0; off >>= 1) {
        sum += __shfl_down(sum, off);
        sq  += __shfl_down(sq, off);
    }
    __shared__ float ls[4], lq[4];
    const int wid = tid >> 6, lane = tid & 63;
    if (lane == 0) { ls[wid] = sum; lq[wid] = sq; }
    __syncthreads();
    if (tid == 0) {
        float S = 0.f, Q = 0.f;
        #pragma unroll
        for (int w = 0; w < 4; ++w) { S += ls[w]; Q += lq[w]; }
        ls[0] = S; lq[0] = Q;
    }
    __syncthreads();
    const float mu = ls[0] * (1.f / 512.f);
    const float var = lq[0] * (1.f / 512.f) - mu * mu;
    const float rs = rsqrtf(var + 1e-5f);

    float* yr = y + (size_t)row * En;
    yr[tid]       = (a - mu) * rs * gamma[tid]       + beta[tid];
    yr[tid + 256] = (b - mu) * rs * gamma[tid + 256] + beta[tid + 256];
}

// ---------------------------------------------------------------------------
extern "C" void kernel_launch(void* const* d_in, const int* in_sizes, int n_in,
                              void* d_out, int out_size, void* d_ws, size_t ws_size,
                              hipStream_t stream)
{
    const float* x     = (const float*)d_in[0];
    const float* Wq    = (const float*)d_in[1];
    const float* Wk    = (const float*)d_in[2];
    const float* Wv    = (const float*)d_in[3];
    const float* Wp    = (const float*)d_in[4];
    const float* bp    = (const float*)d_in[5];
    const float* gamma = (const float*)d_in[6];
    const float* beta  = (const float*)d_in[7];
    // d_in[8] = mask (int32 tril) — causal, applied analytically.

    float* ws   = (float*)d_ws;
    float* qkv  = ws;                        // 3 * PLANE floats (24 MB)
    float* vals = ws + (size_t)3 * PLANE;    // Mn*En floats (8 MB)
    float* outp = vals + (size_t)Mn * En;    // Mn*En floats (8 MB)

    const int attn_lds = 17024 * 4;          // 68,096 B dynamic LDS
    hipFuncSetAttribute((const void*)attn,
                        hipFuncAttributeMaxDynamicSharedMemorySize, attn_lds);

    qkv_gemm<<<dim3(Mn / 64, (3 * En) / 64), 256, 0, stream>>>(x, Wq, Wk, Wv, qkv);
    attn<<<dim3(512), 256, attn_lds, stream>>>(qkv, vals);
    out_gemm<<<dim3(Mn / 64, En / 64), 256, 0, stream>>>(vals, Wp, bp, x, outp);
    ln_kernel<<<dim3(Mn), 256, 0, stream>>>(outp, gamma, beta, (float*)d_out);
}

// Round 4
// 360.599 us; speedup vs baseline: 6.5178x; 1.3220x over previous
//
#include <hip/hip_runtime.h>

// Problem constants
constexpr int Bn = 2;
constexpr int Sn = 2048;
constexpr int En = 512;
constexpr int Hn = 8;
constexpr int Dn = 64;
constexpr int Mn = Bn * Sn;              // 4096 rows
constexpr int PLANE = Bn * Hn * Sn * Dn; // 2,097,152 elements per q/k/v plane

typedef short bf8 __attribute__((ext_vector_type(8)));
typedef float f32x4 __attribute__((ext_vector_type(4)));

__device__ __forceinline__ unsigned short f2bf(float f) {
    unsigned int u = __float_as_uint(f);
    unsigned int r = 0x7FFFu + ((u >> 16) & 1u);
    return (unsigned short)((u + r) >> 16);
}
__device__ __forceinline__ float bf2f(unsigned short u) {
    return __uint_as_float(((unsigned int)u) << 16);
}
__device__ __forceinline__ void split2(float f, unsigned short& hi, unsigned short& lo) {
    hi = f2bf(f);
    lo = f2bf(f - bf2f(hi));
}

// ---------------------------------------------------------------------------
// Kernel 1 (v2): fused QKV projection via split-bf16 MFMA.
// C[m][n] = sum_k x[m][k] * W[k][n],  M=4096, N=1536 (3 proj x 8 heads x 64),
// K=512. Block: 128x128, BK=32, 256 threads = 4 waves of 64x64.
// A = x staged row-major [m][k]; B = W staged TRANSPOSED [n][k] (coalesced
// column loads). Both as hi/lo bf16 planes; 3 MFMAs per tile (drop lo*lo).
// ---------------------------------------------------------------------------
__global__ __launch_bounds__(256)
void qkv_gemm(const float* __restrict__ x,
              const float* __restrict__ Wq,
              const float* __restrict__ Wk,
              const float* __restrict__ Wv,
              float* __restrict__ qkv)
{
    __shared__ unsigned short Ah[128][40], Al[128][40];
    __shared__ unsigned short Bh[128][40], Bl[128][40];

    const int tid = threadIdx.x;
    const int m0 = blockIdx.x * 128;
    const int n0 = blockIdx.y * 128;      // never straddles a proj boundary
    const int proj = n0 >> 9;
    const int within = n0 & 511;
    const float* W = (proj == 0) ? Wq : (proj == 1) ? Wk : Wv;

    const int wave = tid >> 6, lane = tid & 63;
    const int wm = (wave >> 1) * 64, wn = (wave & 1) * 64;
    const int lm = lane & 15, quad = lane >> 4;

    // staging assignments
    const int am = tid >> 1;              // 0..127
    const int aks = (tid & 1) * 16;       // 0 or 16
    const float* arow = x + (size_t)(m0 + am) * En + aks;

    const int nn = tid & 127;             // 0..127
    const int bkg = (tid >> 7) * 16;      // 0 or 16
    const int ng = within + nn;
    const float* bcol = W + (size_t)(ng >> 6) * (En * Dn) + (ng & 63);

    f32x4 acc[4][4];
    #pragma unroll
    for (int i = 0; i < 4; ++i)
        #pragma unroll
        for (int j = 0; j < 4; ++j) acc[i][j] = (f32x4){0.f, 0.f, 0.f, 0.f};

    for (int k0 = 0; k0 < En; k0 += 32) {
        // ---- stage A: 16 floats per thread
        {
            float av[16];
            *(float4*)&av[0]  = *(const float4*)(arow + k0);
            *(float4*)&av[4]  = *(const float4*)(arow + k0 + 4);
            *(float4*)&av[8]  = *(const float4*)(arow + k0 + 8);
            *(float4*)&av[12] = *(const float4*)(arow + k0 + 12);
            unsigned short hi[16], lo[16];
            #pragma unroll
            for (int j = 0; j < 16; ++j) split2(av[j], hi[j], lo[j]);
            *(bf8*)&Ah[am][aks]     = *(bf8*)&hi[0];
            *(bf8*)&Ah[am][aks + 8] = *(bf8*)&hi[8];
            *(bf8*)&Al[am][aks]     = *(bf8*)&lo[0];
            *(bf8*)&Al[am][aks + 8] = *(bf8*)&lo[8];
        }
        // ---- stage B (transpose-on-stage): 16 strided floats per thread
        {
            float bv[16];
            #pragma unroll
            for (int j = 0; j < 16; ++j)
                bv[j] = bcol[(size_t)(k0 + bkg + j) * Dn];
            unsigned short hi[16], lo[16];
            #pragma unroll
            for (int j = 0; j < 16; ++j) split2(bv[j], hi[j], lo[j]);
            *(bf8*)&Bh[nn][bkg]     = *(bf8*)&hi[0];
            *(bf8*)&Bh[nn][bkg + 8] = *(bf8*)&hi[8];
            *(bf8*)&Bl[nn][bkg]     = *(bf8*)&lo[0];
            *(bf8*)&Bl[nn][bkg + 8] = *(bf8*)&lo[8];
        }
        __syncthreads();

        bf8 a_h[4], a_l[4], b_h[4], b_l[4];
        #pragma unroll
        for (int mi = 0; mi < 4; ++mi) {
            a_h[mi] = *(const bf8*)&Ah[wm + mi * 16 + lm][quad * 8];
            a_l[mi] = *(const bf8*)&Al[wm + mi * 16 + lm][quad * 8];
        }
        #pragma unroll
        for (int ni = 0; ni < 4; ++ni) {
            b_h[ni] = *(const bf8*)&Bh[wn + ni * 16 + lm][quad * 8];
            b_l[ni] = *(const bf8*)&Bl[wn + ni * 16 + lm][quad * 8];
        }
        #pragma unroll
        for (int mi = 0; mi < 4; ++mi)
            #pragma unroll
            for (int ni = 0; ni < 4; ++ni) {
                acc[mi][ni] = __builtin_amdgcn_mfma_f32_16x16x32_bf16(a_h[mi], b_h[ni], acc[mi][ni], 0, 0, 0);
                acc[mi][ni] = __builtin_amdgcn_mfma_f32_16x16x32_bf16(a_h[mi], b_l[ni], acc[mi][ni], 0, 0, 0);
                acc[mi][ni] = __builtin_amdgcn_mfma_f32_16x16x32_bf16(a_l[mi], b_h[ni], acc[mi][ni], 0, 0, 0);
            }
        __syncthreads();
    }

    // epilogue: C/D layout col = lane&15, row = quad*4 + r
    float* base = qkv + (size_t)proj * PLANE;
    #pragma unroll
    for (int mi = 0; mi < 4; ++mi) {
        #pragma unroll
        for (int r = 0; r < 4; ++r) {
            const int m = m0 + wm + mi * 16 + quad * 4 + r;
            const int b = m >> 11;
            const int s = m & 2047;
            #pragma unroll
            for (int ni = 0; ni < 4; ++ni) {
                const int nl = within + wn + ni * 16 + lm;
                const int h = nl >> 6, d = nl & 63;
                base[(((size_t)(b * Hn + h) * Sn + s) * Dn) + d] = acc[mi][ni][r];
            }
        }
    }
}

// ---------------------------------------------------------------------------
// Kernel 2: block-level flash attention (unchanged from R3).
// ---------------------------------------------------------------------------
__global__ __launch_bounds__(256)
void attn(const float* __restrict__ qkv, float* __restrict__ vals)
{
    extern __shared__ float smem[];
    float (*qt_s)[64] = (float(*)[64])(smem);                 // [d][r]
    float (*kt_s)[64] = (float(*)[64])(smem + 4096);          // [d][t]
    float (*vt_s)[68] = (float(*)[68])(smem + 8192);          // [t][d]
    float (*st_s)[68] = (float(*)[68])(smem + 8192 + 4352);   // [r][t]
    float* alf_s  = smem + 8192 + 8704;                       // [64]
    float* linv_s = alf_s + 64;                               // [64]

    const int bidx = blockIdx.x;
    const int jj_ = bidx >> 4;
    const int bh = bidx & 15;
    const int qt = (jj_ < 16) ? jj_ : 47 - jj_;
    const int b = bh >> 3, h = bh & 7;
    const int tid = threadIdx.x;
    const int ty = tid >> 4, tx = tid & 15;
    const int ty4 = ty * 4, tx4 = tx * 4;

    const float* qg = qkv + ((size_t)bh * Sn + (size_t)qt * 64) * Dn;
    const float* kg = qkv + (size_t)PLANE + (size_t)bh * Sn * Dn;
    const float* vg = qkv + (size_t)2 * PLANE + (size_t)bh * Sn * Dn;

    {
        const int qrow = tid >> 2, dg = tid & 3;
        #pragma unroll
        for (int c = 0; c < 4; ++c) {
            float4 v = *(const float4*)(qg + (size_t)qrow * Dn + dg * 16 + 4 * c);
            qt_s[dg * 16 + 4 * c + 0][qrow] = v.x;
            qt_s[dg * 16 + 4 * c + 1][qrow] = v.y;
            qt_s[dg * 16 + 4 * c + 2][qrow] = v.z;
            qt_s[dg * 16 + 4 * c + 3][qrow] = v.w;
        }
    }

    float o[4][4] = {};
    float m = -INFINITY, l = 0.f;
    const int r_b = tid >> 2, dg_b = tid & 3;

    const int ntk = qt + 1;
    for (int it = 0; it < ntk; ++it) {
        const int t0 = it * 64;
        __syncthreads();
        {
            const int trow = tid >> 2, dg = tid & 3;
            const float* kr = kg + (size_t)(t0 + trow) * Dn + dg * 16;
            const float* vr = vg + (size_t)(t0 + trow) * Dn + dg * 16;
            #pragma unroll
            for (int c = 0; c < 4; ++c) {
                float4 kv = *(const float4*)(kr + 4 * c);
                kt_s[dg * 16 + 4 * c + 0][trow] = kv.x;
                kt_s[dg * 16 + 4 * c + 1][trow] = kv.y;
                kt_s[dg * 16 + 4 * c + 2][trow] = kv.z;
                kt_s[dg * 16 + 4 * c + 3][trow] = kv.w;
                *(float4*)&vt_s[trow][dg * 16 + 4 * c] = *(const float4*)(vr + 4 * c);
            }
        }
        __syncthreads();

        {
            float acc[4][4] = {};
            #pragma unroll 8
            for (int kk = 0; kk < 64; ++kk) {
                float4 a = *(const float4*)&qt_s[kk][ty4];
                float4 bq = *(const float4*)&kt_s[kk][tx4];
                float av[4] = {a.x, a.y, a.z, a.w};
                float bv[4] = {bq.x, bq.y, bq.z, bq.w};
                #pragma unroll
                for (int i = 0; i < 4; ++i)
                    #pragma unroll
                    for (int jx = 0; jx < 4; ++jx)
                        acc[i][jx] += av[i] * bv[jx];
            }
            const int toff = t0 - qt * 64;
            #pragma unroll
            for (int i = 0; i < 4; ++i) {
                float4 w;
                w.x = (tx4 + 0 + toff > ty4 + i) ? -INFINITY : acc[i][0];
                w.y = (tx4 + 1 + toff > ty4 + i) ? -INFINITY : acc[i][1];
                w.z = (tx4 + 2 + toff > ty4 + i) ? -INFINITY : acc[i][2];
                w.w = (tx4 + 3 + toff > ty4 + i) ? -INFINITY : acc[i][3];
                *(float4*)&st_s[ty4 + i][tx4] = w;
            }
        }
        __syncthreads();

        {
            float sv[16];
            #pragma unroll
            for (int c = 0; c < 4; ++c) {
                float4 t4v = *(const float4*)&st_s[r_b][dg_b * 16 + 4 * c];
                sv[4 * c + 0] = t4v.x; sv[4 * c + 1] = t4v.y;
                sv[4 * c + 2] = t4v.z; sv[4 * c + 3] = t4v.w;
            }
            float mt = -INFINITY;
            #pragma unroll
            for (int u = 0; u < 16; ++u) mt = fmaxf(mt, sv[u]);
            mt = fmaxf(mt, __shfl_xor(mt, 1));
            mt = fmaxf(mt, __shfl_xor(mt, 2));
            const float mnew = fmaxf(m, mt);
            const float alpha = __expf(m - mnew);
            float ls = 0.f;
            #pragma unroll
            for (int u = 0; u < 16; ++u) { sv[u] = __expf(sv[u] - mnew); ls += sv[u]; }
            ls += __shfl_xor(ls, 1);
            ls += __shfl_xor(ls, 2);
            l = l * alpha + ls;
            m = mnew;
            #pragma unroll
            for (int c = 0; c < 4; ++c) {
                float4 t4v;
                t4v.x = sv[4 * c + 0]; t4v.y = sv[4 * c + 1];
                t4v.z = sv[4 * c + 2]; t4v.w = sv[4 * c + 3];
                *(float4*)&st_s[r_b][dg_b * 16 + 4 * c] = t4v;
            }
            if (dg_b == 0) alf_s[r_b] = alpha;
        }
        __syncthreads();

        {
            float al[4];
            #pragma unroll
            for (int i = 0; i < 4; ++i) al[i] = alf_s[ty4 + i];
            #pragma unroll
            for (int i = 0; i < 4; ++i)
                #pragma unroll
                for (int jx = 0; jx < 4; ++jx) o[i][jx] *= al[i];
            #pragma unroll 4
            for (int t4 = 0; t4 < 64; t4 += 4) {
                float wv[4][4], vv[4][4];
                #pragma unroll
                for (int i = 0; i < 4; ++i) {
                    float4 w = *(const float4*)&st_s[ty4 + i][t4];
                    wv[i][0] = w.x; wv[i][1] = w.y; wv[i][2] = w.z; wv[i][3] = w.w;
                }
                #pragma unroll
                for (int u = 0; u < 4; ++u) {
                    float4 v = *(const float4*)&vt_s[t4 + u][tx4];
                    vv[u][0] = v.x; vv[u][1] = v.y; vv[u][2] = v.z; vv[u][3] = v.w;
                }
                #pragma unroll
                for (int u = 0; u < 4; ++u)
                    #pragma unroll
                    for (int i = 0; i < 4; ++i)
                        #pragma unroll
                        for (int jx = 0; jx < 4; ++jx)
                            o[i][jx] += wv[i][u] * vv[u][jx];
            }
        }
    }

    __syncthreads();
    if (dg_b == 0) linv_s[r_b] = 1.f / l;
    __syncthreads();

    #pragma unroll
    for (int i = 0; i < 4; ++i) {
        const float li = linv_s[ty4 + i];
        float4 w;
        w.x = o[i][0] * li; w.y = o[i][1] * li;
        w.z = o[i][2] * li; w.w = o[i][3] * li;
        float* dst = vals + ((size_t)(b * Sn + qt * 64 + ty4 + i)) * En
                     + (size_t)(7 - h) * 64 + tx4;
        *(float4*)dst = w;
    }
}

// ---------------------------------------------------------------------------
// Kernel 3 (v2): out = vals @ Wp^T + bp + x via split-bf16 MFMA.
// C[m][n] = sum_k vals[m][k] * Wp[n][k]. M=4096, N=512, K=512.
// Block: 64x128, BK=32, 256 threads = 4 waves of 32x64. Wp already [n][k].
// ---------------------------------------------------------------------------
__global__ __launch_bounds__(256)
void out_gemm(const float* __restrict__ vals,
              const float* __restrict__ Wp,
              const float* __restrict__ bp,
              const float* __restrict__ x,
              float* __restrict__ outp)
{
    __shared__ unsigned short Ah[64][40], Al[64][40];
    __shared__ unsigned short Bh[128][40], Bl[128][40];

    const int tid = threadIdx.x;
    const int m0 = blockIdx.x * 64;
    const int n0 = blockIdx.y * 128;

    const int wave = tid >> 6, lane = tid & 63;
    const int wm = (wave >> 1) * 32, wn = (wave & 1) * 64;
    const int lm = lane & 15, quad = lane >> 4;

    const int am = tid >> 2;              // 0..63
    const int aks = (tid & 3) * 8;        // 0,8,16,24
    const float* arow = vals + (size_t)(m0 + am) * En + aks;

    const int bn = tid >> 1;              // 0..127
    const int bks = (tid & 1) * 16;       // 0 or 16
    const float* brow = Wp + (size_t)(n0 + bn) * En + bks;

    f32x4 acc[2][4];
    #pragma unroll
    for (int i = 0; i < 2; ++i)
        #pragma unroll
        for (int j = 0; j < 4; ++j) acc[i][j] = (f32x4){0.f, 0.f, 0.f, 0.f};

    for (int k0 = 0; k0 < En; k0 += 32) {
        {
            float av[8];
            *(float4*)&av[0] = *(const float4*)(arow + k0);
            *(float4*)&av[4] = *(const float4*)(arow + k0 + 4);
            unsigned short hi[8], lo[8];
            #pragma unroll
            for (int j = 0; j < 8; ++j) split2(av[j], hi[j], lo[j]);
            *(bf8*)&Ah[am][aks] = *(bf8*)&hi[0];
            *(bf8*)&Al[am][aks] = *(bf8*)&lo[0];
        }
        {
            float bv[16];
            *(float4*)&bv[0]  = *(const float4*)(brow + k0);
            *(float4*)&bv[4]  = *(const float4*)(brow + k0 + 4);
            *(float4*)&bv[8]  = *(const float4*)(brow + k0 + 8);
            *(float4*)&bv[12] = *(const float4*)(brow + k0 + 12);
            unsigned short hi[16], lo[16];
            #pragma unroll
            for (int j = 0; j < 16; ++j) split2(bv[j], hi[j], lo[j]);
            *(bf8*)&Bh[bn][bks]     = *(bf8*)&hi[0];
            *(bf8*)&Bh[bn][bks + 8] = *(bf8*)&hi[8];
            *(bf8*)&Bl[bn][bks]     = *(bf8*)&lo[0];
            *(bf8*)&Bl[bn][bks + 8] = *(bf8*)&lo[8];
        }
        __syncthreads();

        bf8 a_h[2], a_l[2], b_h[4], b_l[4];
        #pragma unroll
        for (int mi = 0; mi < 2; ++mi) {
            a_h[mi] = *(const bf8*)&Ah[wm + mi * 16 + lm][quad * 8];
            a_l[mi] = *(const bf8*)&Al[wm + mi * 16 + lm][quad * 8];
        }
        #pragma unroll
        for (int ni = 0; ni < 4; ++ni) {
            b_h[ni] = *(const bf8*)&Bh[wn + ni * 16 + lm][quad * 8];
            b_l[ni] = *(const bf8*)&Bl[wn + ni * 16 + lm][quad * 8];
        }
        #pragma unroll
        for (int mi = 0; mi < 2; ++mi)
            #pragma unroll
            for (int ni = 0; ni < 4; ++ni) {
                acc[mi][ni] = __builtin_amdgcn_mfma_f32_16x16x32_bf16(a_h[mi], b_h[ni], acc[mi][ni], 0, 0, 0);
                acc[mi][ni] = __builtin_amdgcn_mfma_f32_16x16x32_bf16(a_h[mi], b_l[ni], acc[mi][ni], 0, 0, 0);
                acc[mi][ni] = __builtin_amdgcn_mfma_f32_16x16x32_bf16(a_l[mi], b_h[ni], acc[mi][ni], 0, 0, 0);
            }
        __syncthreads();
    }

    #pragma unroll
    for (int mi = 0; mi < 2; ++mi) {
        #pragma unroll
        for (int r = 0; r < 4; ++r) {
            const int m = m0 + wm + mi * 16 + quad * 4 + r;
            #pragma unroll
            for (int ni = 0; ni < 4; ++ni) {
                const int n = n0 + wn + ni * 16 + lm;
                const size_t idx = (size_t)m * En + n;
                outp[idx] = acc[mi][ni][r] + bp[n] + x[idx];
            }
        }
    }
}

// ---------------------------------------------------------------------------
// Kernel 4: row-wise LayerNorm (unchanged).
// ---------------------------------------------------------------------------
__global__ __launch_bounds__(256)
void ln_kernel(const float* __restrict__ outp,
               const float* __restrict__ gamma,
               const float* __restrict__ beta,
               float* __restrict__ y)
{
    const int row = blockIdx.x;
    const int tid = threadIdx.x;
    const float* r = outp + (size_t)row * En;

    const float a = r[tid];
    const float b = r[tid + 256];
    float sum = a + b;
    float sq = a * a + b * b;
    #pragma unroll
    for (int off = 32; off > 0; off >>= 1) {
        sum += __shfl_down(sum, off);
        sq  += __shfl_down(sq, off);
    }
    __shared__ float ls[4], lq[4];
    const int wid = tid >> 6, lane = tid & 63;
    if (lane == 0) { ls[wid] = sum; lq[wid] = sq; }
    __syncthreads();
    if (tid == 0) {
        float S = 0.f, Q = 0.f;
        #pragma unroll
        for (int w = 0; w < 4; ++w) { S += ls[w]; Q += lq[w]; }
        ls[0] = S; lq[0] = Q;
    }
    __syncthreads();
    const float mu = ls[0] * (1.f / 512.f);
    const float var = lq[0] * (1.f / 512.f) - mu * mu;
    const float rs = rsqrtf(var + 1e-5f);

    float* yr = y + (size_t)row * En;
    yr[tid]       = (a - mu) * rs * gamma[tid]       + beta[tid];
    yr[tid + 256] = (b - mu) * rs * gamma[tid + 256] + beta[tid + 256];
}

// ---------------------------------------------------------------------------
extern "C" void kernel_launch(void* const* d_in, const int* in_sizes, int n_in,
                              void* d_out, int out_size, void* d_ws, size_t ws_size,
                              hipStream_t stream)
{
    const float* x     = (const float*)d_in[0];
    const float* Wq    = (const float*)d_in[1];
    const float* Wk    = (const float*)d_in[2];
    const float* Wv    = (const float*)d_in[3];
    const float* Wp    = (const float*)d_in[4];
    const float* bp    = (const float*)d_in[5];
    const float* gamma = (const float*)d_in[6];
    const float* beta  = (const float*)d_in[7];
    // d_in[8] = mask (int32 tril) — causal, applied analytically.

    float* ws   = (float*)d_ws;
    float* qkv  = ws;                        // 3 * PLANE floats (24 MB)
    float* vals = ws + (size_t)3 * PLANE;    // Mn*En floats (8 MB)
    float* outp = vals + (size_t)Mn * En;    // Mn*En floats (8 MB)

    const int attn_lds = 17024 * 4;          // 68,096 B dynamic LDS
    hipFuncSetAttribute((const void*)attn,
                        hipFuncAttributeMaxDynamicSharedMemorySize, attn_lds);

    qkv_gemm<<<dim3(Mn / 128, (3 * En) / 128), 256, 0, stream>>>(x, Wq, Wk, Wv, qkv);
    attn<<<dim3(512), 256, attn_lds, stream>>>(qkv, vals);
    out_gemm<<<dim3(Mn / 64, En / 128), 256, 0, stream>>>(vals, Wp, bp, x, outp);
    ln_kernel<<<dim3(Mn), 256, 0, stream>>>(outp, gamma, beta, (float*)d_out);
}

// Round 5
// 222.473 us; speedup vs baseline: 10.5645x; 1.6209x over previous
//
#include <hip/hip_runtime.h>

// Problem constants
constexpr int Bn = 2;
constexpr int Sn = 2048;
constexpr int En = 512;
constexpr int Hn = 8;
constexpr int Dn = 64;
constexpr int Mn = Bn * Sn;              // 4096 rows
constexpr int PLANE = Bn * Hn * Sn * Dn; // 2,097,152 elements per q/k/v plane

typedef short bf8 __attribute__((ext_vector_type(8)));
typedef float f32x4 __attribute__((ext_vector_type(4)));

__device__ __forceinline__ unsigned short f2bf(float f) {
    unsigned int u = __float_as_uint(f);
    unsigned int r = 0x7FFFu + ((u >> 16) & 1u);
    return (unsigned short)((u + r) >> 16);
}
__device__ __forceinline__ float bf2f(unsigned short u) {
    return __uint_as_float(((unsigned int)u) << 16);
}
__device__ __forceinline__ void split2(float f, unsigned short& hi, unsigned short& lo) {
    hi = f2bf(f);
    lo = f2bf(f - bf2f(hi));
}

// ---------------------------------------------------------------------------
// Kernel 1: fused QKV projection via split-bf16 MFMA (unchanged from R4).
// ---------------------------------------------------------------------------
__global__ __launch_bounds__(256)
void qkv_gemm(const float* __restrict__ x,
              const float* __restrict__ Wq,
              const float* __restrict__ Wk,
              const float* __restrict__ Wv,
              float* __restrict__ qkv)
{
    __shared__ unsigned short Ah[128][40], Al[128][40];
    __shared__ unsigned short Bh[128][40], Bl[128][40];

    const int tid = threadIdx.x;
    const int m0 = blockIdx.x * 128;
    const int n0 = blockIdx.y * 128;
    const int proj = n0 >> 9;
    const int within = n0 & 511;
    const float* W = (proj == 0) ? Wq : (proj == 1) ? Wk : Wv;

    const int wave = tid >> 6, lane = tid & 63;
    const int wm = (wave >> 1) * 64, wn = (wave & 1) * 64;
    const int lm = lane & 15, quad = lane >> 4;

    const int am = tid >> 1;
    const int aks = (tid & 1) * 16;
    const float* arow = x + (size_t)(m0 + am) * En + aks;

    const int nn = tid & 127;
    const int bkg = (tid >> 7) * 16;
    const int ng = within + nn;
    const float* bcol = W + (size_t)(ng >> 6) * (En * Dn) + (ng & 63);

    f32x4 acc[4][4];
    #pragma unroll
    for (int i = 0; i < 4; ++i)
        #pragma unroll
        for (int j = 0; j < 4; ++j) acc[i][j] = (f32x4){0.f, 0.f, 0.f, 0.f};

    for (int k0 = 0; k0 < En; k0 += 32) {
        {
            float av[16];
            *(float4*)&av[0]  = *(const float4*)(arow + k0);
            *(float4*)&av[4]  = *(const float4*)(arow + k0 + 4);
            *(float4*)&av[8]  = *(const float4*)(arow + k0 + 8);
            *(float4*)&av[12] = *(const float4*)(arow + k0 + 12);
            unsigned short hi[16], lo[16];
            #pragma unroll
            for (int j = 0; j < 16; ++j) split2(av[j], hi[j], lo[j]);
            *(bf8*)&Ah[am][aks]     = *(bf8*)&hi[0];
            *(bf8*)&Ah[am][aks + 8] = *(bf8*)&hi[8];
            *(bf8*)&Al[am][aks]     = *(bf8*)&lo[0];
            *(bf8*)&Al[am][aks + 8] = *(bf8*)&lo[8];
        }
        {
            float bv[16];
            #pragma unroll
            for (int j = 0; j < 16; ++j)
                bv[j] = bcol[(size_t)(k0 + bkg + j) * Dn];
            unsigned short hi[16], lo[16];
            #pragma unroll
            for (int j = 0; j < 16; ++j) split2(bv[j], hi[j], lo[j]);
            *(bf8*)&Bh[nn][bkg]     = *(bf8*)&hi[0];
            *(bf8*)&Bh[nn][bkg + 8] = *(bf8*)&hi[8];
            *(bf8*)&Bl[nn][bkg]     = *(bf8*)&lo[0];
            *(bf8*)&Bl[nn][bkg + 8] = *(bf8*)&lo[8];
        }
        __syncthreads();

        bf8 a_h[4], a_l[4], b_h[4], b_l[4];
        #pragma unroll
        for (int mi = 0; mi < 4; ++mi) {
            a_h[mi] = *(const bf8*)&Ah[wm + mi * 16 + lm][quad * 8];
            a_l[mi] = *(const bf8*)&Al[wm + mi * 16 + lm][quad * 8];
        }
        #pragma unroll
        for (int ni = 0; ni < 4; ++ni) {
            b_h[ni] = *(const bf8*)&Bh[wn + ni * 16 + lm][quad * 8];
            b_l[ni] = *(const bf8*)&Bl[wn + ni * 16 + lm][quad * 8];
        }
        #pragma unroll
        for (int mi = 0; mi < 4; ++mi)
            #pragma unroll
            for (int ni = 0; ni < 4; ++ni) {
                acc[mi][ni] = __builtin_amdgcn_mfma_f32_16x16x32_bf16(a_h[mi], b_h[ni], acc[mi][ni], 0, 0, 0);
                acc[mi][ni] = __builtin_amdgcn_mfma_f32_16x16x32_bf16(a_h[mi], b_l[ni], acc[mi][ni], 0, 0, 0);
                acc[mi][ni] = __builtin_amdgcn_mfma_f32_16x16x32_bf16(a_l[mi], b_h[ni], acc[mi][ni], 0, 0, 0);
            }
        __syncthreads();
    }

    float* base = qkv + (size_t)proj * PLANE;
    #pragma unroll
    for (int mi = 0; mi < 4; ++mi) {
        #pragma unroll
        for (int r = 0; r < 4; ++r) {
            const int m = m0 + wm + mi * 16 + quad * 4 + r;
            const int b = m >> 11;
            const int s = m & 2047;
            #pragma unroll
            for (int ni = 0; ni < 4; ++ni) {
                const int nl = within + wn + ni * 16 + lm;
                const int h = nl >> 6, d = nl & 63;
                base[(((size_t)(b * Hn + h) * Sn + s) * Dn) + d] = acc[mi][ni][r];
            }
        }
    }
}

// ---------------------------------------------------------------------------
// Kernel 2 (v3): MFMA flash attention.
// 256 threads = 4 waves per (b,h,64-row Q-tile). Wave w owns q rows
// w*16..w*16+15. Per 64-wide K-tile:
//   scores: S^T = K Q^T via split-bf16 mfma_16x16x32 (3 MFMAs/chunk).
//           C-layout: col=q=lane&15, row=t=quad*4+r -> softmax needs only
//           per-lane reduction over 16 regs + shfl_xor(16,32) across quads.
//   softmax: online m/l per q (register-resident, replicated across quads).
//   P: bf16, wave-local LDS round-trip [q][t] (b64-packed writes).
//   PV: O += P V, A=P[q][t], B=vT[d][t] (V staged transposed), plain bf16.
// LDS rows padded to 72 bf16 (36 words) -> <=2-way bank aliasing (free).
// Total LDS 55,808 B -> 2 blocks/CU.
// ---------------------------------------------------------------------------
__global__ __launch_bounds__(256)
void attn(const float* __restrict__ qkv, float* __restrict__ vals)
{
    extern __shared__ unsigned short sm[];
    unsigned short (*qh)[72] = (unsigned short(*)[72])(sm);           // [q][d] hi
    unsigned short (*ql)[72] = (unsigned short(*)[72])(sm + 4608);    // [q][d] lo
    unsigned short (*kh)[72] = (unsigned short(*)[72])(sm + 9216);    // [t][d] hi
    unsigned short (*kl)[72] = (unsigned short(*)[72])(sm + 13824);   // [t][d] lo
    unsigned short (*vT)[72] = (unsigned short(*)[72])(sm + 18432);   // [d][t]
    unsigned short (*pt)[72] = (unsigned short(*)[72])(sm + 23040);   // [q][t]
    float* alf  = (float*)(sm + 27648);                               // [64]
    float* linv = alf + 64;                                           // [64]

    const int bidx = blockIdx.x;
    const int jj_ = bidx >> 4;
    const int bh = bidx & 15;
    const int qt = (jj_ < 16) ? jj_ : 47 - jj_;   // complementary pairing
    const int b = bh >> 3, h = bh & 7;
    const int tid = threadIdx.x;
    const int wave = tid >> 6, lane = tid & 63;
    const int quad = lane >> 4, lq = lane & 15;

    const float* qg = qkv + ((size_t)bh * Sn + (size_t)qt * 64) * Dn;
    const float* kg = qkv + (size_t)PLANE + (size_t)bh * Sn * Dn;
    const float* vg = qkv + (size_t)2 * PLANE + (size_t)bh * Sn * Dn;

    const int srow = tid & 63;           // staging row
    const int sdg  = tid >> 6;           // staging d-group (0..3)*16

    // ---- stage Q (once): hi/lo split into qh/ql[q][d]
    {
        const float* qr = qg + (size_t)srow * Dn + sdg * 16;
        float av[16];
        *(float4*)&av[0]  = *(const float4*)(qr);
        *(float4*)&av[4]  = *(const float4*)(qr + 4);
        *(float4*)&av[8]  = *(const float4*)(qr + 8);
        *(float4*)&av[12] = *(const float4*)(qr + 12);
        unsigned short hi[16], lo[16];
        #pragma unroll
        for (int j = 0; j < 16; ++j) split2(av[j], hi[j], lo[j]);
        *(bf8*)&qh[srow][sdg * 16]     = *(bf8*)&hi[0];
        *(bf8*)&qh[srow][sdg * 16 + 8] = *(bf8*)&hi[8];
        *(bf8*)&ql[srow][sdg * 16]     = *(bf8*)&lo[0];
        *(bf8*)&ql[srow][sdg * 16 + 8] = *(bf8*)&lo[8];
    }
    __syncthreads();

    // Q fragments (B operand), hoisted: chunk c covers d = c*32..c*32+31
    bf8 qfh[2], qfl[2];
    #pragma unroll
    for (int c = 0; c < 2; ++c) {
        qfh[c] = *(const bf8*)&qh[wave * 16 + lq][c * 32 + quad * 8];
        qfl[c] = *(const bf8*)&ql[wave * 16 + lq][c * 32 + quad * 8];
    }

    f32x4 accO[4];
    #pragma unroll
    for (int nj = 0; nj < 4; ++nj) accO[nj] = (f32x4){0.f, 0.f, 0.f, 0.f};
    float m = -INFINITY, l = 0.f;

    const int ntk = qt + 1;
    for (int it = 0; it < ntk; ++it) {
        const int t0 = it * 64;
        __syncthreads();   // prev tile fully consumed before restaging
        // ---- stage K (hi/lo) and V (transposed, plain bf16)
        {
            const float* kr = kg + (size_t)(t0 + srow) * Dn + sdg * 16;
            float av[16];
            *(float4*)&av[0]  = *(const float4*)(kr);
            *(float4*)&av[4]  = *(const float4*)(kr + 4);
            *(float4*)&av[8]  = *(const float4*)(kr + 8);
            *(float4*)&av[12] = *(const float4*)(kr + 12);
            unsigned short hi[16], lo[16];
            #pragma unroll
            for (int j = 0; j < 16; ++j) split2(av[j], hi[j], lo[j]);
            *(bf8*)&kh[srow][sdg * 16]     = *(bf8*)&hi[0];
            *(bf8*)&kh[srow][sdg * 16 + 8] = *(bf8*)&hi[8];
            *(bf8*)&kl[srow][sdg * 16]     = *(bf8*)&lo[0];
            *(bf8*)&kl[srow][sdg * 16 + 8] = *(bf8*)&lo[8];

            const float* vr = vg + (size_t)(t0 + srow) * Dn + sdg * 16;
            float vv[16];
            *(float4*)&vv[0]  = *(const float4*)(vr);
            *(float4*)&vv[4]  = *(const float4*)(vr + 4);
            *(float4*)&vv[8]  = *(const float4*)(vr + 8);
            *(float4*)&vv[12] = *(const float4*)(vr + 12);
            #pragma unroll
            for (int j = 0; j < 16; ++j)
                vT[sdg * 16 + j][srow] = f2bf(vv[j]);
        }
        __syncthreads();

        // ---- scores: S^T = K Q^T (split-bf16)
        f32x4 accS[4];
        #pragma unroll
        for (int mi = 0; mi < 4; ++mi) accS[mi] = (f32x4){0.f, 0.f, 0.f, 0.f};
        #pragma unroll
        for (int mi = 0; mi < 4; ++mi) {
            #pragma unroll
            for (int c = 0; c < 2; ++c) {
                bf8 ah = *(const bf8*)&kh[mi * 16 + lq][c * 32 + quad * 8];
                bf8 al = *(const bf8*)&kl[mi * 16 + lq][c * 32 + quad * 8];
                accS[mi] = __builtin_amdgcn_mfma_f32_16x16x32_bf16(ah, qfh[c], accS[mi], 0, 0, 0);
                accS[mi] = __builtin_amdgcn_mfma_f32_16x16x32_bf16(ah, qfl[c], accS[mi], 0, 0, 0);
                accS[mi] = __builtin_amdgcn_mfma_f32_16x16x32_bf16(al, qfh[c], accS[mi], 0, 0, 0);
            }
        }

        // ---- causal mask (diagonal tile only): t_local > q_local -> -inf
        if (it == qt) {
            const int qrel = wave * 16 + lq;
            #pragma unroll
            for (int mi = 0; mi < 4; ++mi)
                #pragma unroll
                for (int r = 0; r < 4; ++r)
                    if (mi * 16 + quad * 4 + r > qrel) accS[mi][r] = -INFINITY;
        }

        // ---- online softmax (per q = lane&15; state replicated across quads)
        float mt = -INFINITY;
        #pragma unroll
        for (int mi = 0; mi < 4; ++mi)
            #pragma unroll
            for (int r = 0; r < 4; ++r) mt = fmaxf(mt, accS[mi][r]);
        mt = fmaxf(mt, __shfl_xor(mt, 16));
        mt = fmaxf(mt, __shfl_xor(mt, 32));
        const float mnew = fmaxf(m, mt);
        const float alpha = __expf(m - mnew);    // first tile: exp(-inf)=0
        float ls = 0.f;
        #pragma unroll
        for (int mi = 0; mi < 4; ++mi)
            #pragma unroll
            for (int r = 0; r < 4; ++r) {
                const float p = __expf(accS[mi][r] - mnew);
                accS[mi][r] = p;
                ls += p;
            }
        ls += __shfl_xor(ls, 16);
        ls += __shfl_xor(ls, 32);
        l = l * alpha + ls;
        m = mnew;

        // ---- P -> LDS (bf16, A-layout source [q][t]); wave-local
        #pragma unroll
        for (int mi = 0; mi < 4; ++mi) {
            ushort4 pk;
            pk.x = f2bf(accS[mi][0]);
            pk.y = f2bf(accS[mi][1]);
            pk.z = f2bf(accS[mi][2]);
            pk.w = f2bf(accS[mi][3]);
            *(ushort4*)&pt[wave * 16 + lq][mi * 16 + quad * 4] = pk;
        }
        if (quad == 0) alf[wave * 16 + lq] = alpha;

        // ---- O rescale + PV
        {
            float4 al4 = *(const float4*)&alf[wave * 16 + quad * 4];
            #pragma unroll
            for (int nj = 0; nj < 4; ++nj) {
                accO[nj][0] *= al4.x;
                accO[nj][1] *= al4.y;
                accO[nj][2] *= al4.z;
                accO[nj][3] *= al4.w;
            }
            #pragma unroll
            for (int c = 0; c < 2; ++c) {
                bf8 pf = *(const bf8*)&pt[wave * 16 + lq][c * 32 + quad * 8];
                #pragma unroll
                for (int nj = 0; nj < 4; ++nj) {
                    bf8 vf = *(const bf8*)&vT[nj * 16 + lq][c * 32 + quad * 8];
                    accO[nj] = __builtin_amdgcn_mfma_f32_16x16x32_bf16(pf, vf, accO[nj], 0, 0, 0);
                }
            }
        }
    }

    if (quad == 0) linv[wave * 16 + lq] = 1.f / l;
    float4 li4 = *(const float4*)&linv[wave * 16 + quad * 4];
    const float lir[4] = {li4.x, li4.y, li4.z, li4.w};

    // ---- epilogue: normalize + head-reversed write
    #pragma unroll
    for (int r = 0; r < 4; ++r) {
        const int s = qt * 64 + wave * 16 + quad * 4 + r;
        float* dst = vals + ((size_t)(b * Sn + s)) * En + (size_t)(7 - h) * 64;
        #pragma unroll
        for (int nj = 0; nj < 4; ++nj)
            dst[nj * 16 + lq] = accO[nj][r] * lir[r];
    }
}

// ---------------------------------------------------------------------------
// Kernel 3: out = vals @ Wp^T + bp + x via split-bf16 MFMA (unchanged).
// ---------------------------------------------------------------------------
__global__ __launch_bounds__(256)
void out_gemm(const float* __restrict__ vals,
              const float* __restrict__ Wp,
              const float* __restrict__ bp,
              const float* __restrict__ x,
              float* __restrict__ outp)
{
    __shared__ unsigned short Ah[64][40], Al[64][40];
    __shared__ unsigned short Bh[128][40], Bl[128][40];

    const int tid = threadIdx.x;
    const int m0 = blockIdx.x * 64;
    const int n0 = blockIdx.y * 128;

    const int wave = tid >> 6, lane = tid & 63;
    const int wm = (wave >> 1) * 32, wn = (wave & 1) * 64;
    const int lm = lane & 15, quad = lane >> 4;

    const int am = tid >> 2;
    const int aks = (tid & 3) * 8;
    const float* arow = vals + (size_t)(m0 + am) * En + aks;

    const int bn = tid >> 1;
    const int bks = (tid & 1) * 16;
    const float* brow = Wp + (size_t)(n0 + bn) * En + bks;

    f32x4 acc[2][4];
    #pragma unroll
    for (int i = 0; i < 2; ++i)
        #pragma unroll
        for (int j = 0; j < 4; ++j) acc[i][j] = (f32x4){0.f, 0.f, 0.f, 0.f};

    for (int k0 = 0; k0 < En; k0 += 32) {
        {
            float av[8];
            *(float4*)&av[0] = *(const float4*)(arow + k0);
            *(float4*)&av[4] = *(const float4*)(arow + k0 + 4);
            unsigned short hi[8], lo[8];
            #pragma unroll
            for (int j = 0; j < 8; ++j) split2(av[j], hi[j], lo[j]);
            *(bf8*)&Ah[am][aks] = *(bf8*)&hi[0];
            *(bf8*)&Al[am][aks] = *(bf8*)&lo[0];
        }
        {
            float bv[16];
            *(float4*)&bv[0]  = *(const float4*)(brow + k0);
            *(float4*)&bv[4]  = *(const float4*)(brow + k0 + 4);
            *(float4*)&bv[8]  = *(const float4*)(brow + k0 + 8);
            *(float4*)&bv[12] = *(const float4*)(brow + k0 + 12);
            unsigned short hi[16], lo[16];
            #pragma unroll
            for (int j = 0; j < 16; ++j) split2(bv[j], hi[j], lo[j]);
            *(bf8*)&Bh[bn][bks]     = *(bf8*)&hi[0];
            *(bf8*)&Bh[bn][bks + 8] = *(bf8*)&hi[8];
            *(bf8*)&Bl[bn][bks]     = *(bf8*)&lo[0];
            *(bf8*)&Bl[bn][bks + 8] = *(bf8*)&lo[8];
        }
        __syncthreads();

        bf8 a_h[2], a_l[2], b_h[4], b_l[4];
        #pragma unroll
        for (int mi = 0; mi < 2; ++mi) {
            a_h[mi] = *(const bf8*)&Ah[wm + mi * 16 + lm][quad * 8];
            a_l[mi] = *(const bf8*)&Al[wm + mi * 16 + lm][quad * 8];
        }
        #pragma unroll
        for (int ni = 0; ni < 4; ++ni) {
            b_h[ni] = *(const bf8*)&Bh[wn + ni * 16 + lm][quad * 8];
            b_l[ni] = *(const bf8*)&Bl[wn + ni * 16 + lm][quad * 8];
        }
        #pragma unroll
        for (int mi = 0; mi < 2; ++mi)
            #pragma unroll
            for (int ni = 0; ni < 4; ++ni) {
                acc[mi][ni] = __builtin_amdgcn_mfma_f32_16x16x32_bf16(a_h[mi], b_h[ni], acc[mi][ni], 0, 0, 0);
                acc[mi][ni] = __builtin_amdgcn_mfma_f32_16x16x32_bf16(a_h[mi], b_l[ni], acc[mi][ni], 0, 0, 0);
                acc[mi][ni] = __builtin_amdgcn_mfma_f32_16x16x32_bf16(a_l[mi], b_h[ni], acc[mi][ni], 0, 0, 0);
            }
        __syncthreads();
    }

    #pragma unroll
    for (int mi = 0; mi < 2; ++mi) {
        #pragma unroll
        for (int r = 0; r < 4; ++r) {
            const int m = m0 + wm + mi * 16 + quad * 4 + r;
            #pragma unroll
            for (int ni = 0; ni < 4; ++ni) {
                const int n = n0 + wn + ni * 16 + lm;
                const size_t idx = (size_t)m * En + n;
                outp[idx] = acc[mi][ni][r] + bp[n] + x[idx];
            }
        }
    }
}

// ---------------------------------------------------------------------------
// Kernel 4: row-wise LayerNorm (unchanged).
// ---------------------------------------------------------------------------
__global__ __launch_bounds__(256)
void ln_kernel(const float* __restrict__ outp,
               const float* __restrict__ gamma,
               const float* __restrict__ beta,
               float* __restrict__ y)
{
    const int row = blockIdx.x;
    const int tid = threadIdx.x;
    const float* r = outp + (size_t)row * En;

    const float a = r[tid];
    const float b = r[tid + 256];
    float sum = a + b;
    float sq = a * a + b * b;
    #pragma unroll
    for (int off = 32; off > 0; off >>= 1) {
        sum += __shfl_down(sum, off);
        sq  += __shfl_down(sq, off);
    }
    __shared__ float ls[4], lq[4];
    const int wid = tid >> 6, lane = tid & 63;
    if (lane == 0) { ls[wid] = sum; lq[wid] = sq; }
    __syncthreads();
    if (tid == 0) {
        float S = 0.f, Q = 0.f;
        #pragma unroll
        for (int w = 0; w < 4; ++w) { S += ls[w]; Q += lq[w]; }
        ls[0] = S; lq[0] = Q;
    }
    __syncthreads();
    const float mu = ls[0] * (1.f / 512.f);
    const float var = lq[0] * (1.f / 512.f) - mu * mu;
    const float rs = rsqrtf(var + 1e-5f);

    float* yr = y + (size_t)row * En;
    yr[tid]       = (a - mu) * rs * gamma[tid]       + beta[tid];
    yr[tid + 256] = (b - mu) * rs * gamma[tid + 256] + beta[tid + 256];
}

// ---------------------------------------------------------------------------
extern "C" void kernel_launch(void* const* d_in, const int* in_sizes, int n_in,
                              void* d_out, int out_size, void* d_ws, size_t ws_size,
                              hipStream_t stream)
{
    const float* x     = (const float*)d_in[0];
    const float* Wq    = (const float*)d_in[1];
    const float* Wk    = (const float*)d_in[2];
    const float* Wv    = (const float*)d_in[3];
    const float* Wp    = (const float*)d_in[4];
    const float* bp    = (const float*)d_in[5];
    const float* gamma = (const float*)d_in[6];
    const float* beta  = (const float*)d_in[7];
    // d_in[8] = mask (int32 tril) — causal, applied analytically.

    float* ws   = (float*)d_ws;
    float* qkv  = ws;                        // 3 * PLANE floats (24 MB)
    float* vals = ws + (size_t)3 * PLANE;    // Mn*En floats (8 MB)
    float* outp = vals + (size_t)Mn * En;    // Mn*En floats (8 MB)

    const int attn_lds = 55808;              // 27648 bf16 + 128 floats
    hipFuncSetAttribute((const void*)attn,
                        hipFuncAttributeMaxDynamicSharedMemorySize, attn_lds);

    qkv_gemm<<<dim3(Mn / 128, (3 * En) / 128), 256, 0, stream>>>(x, Wq, Wk, Wv, qkv);
    attn<<<dim3(512), 256, attn_lds, stream>>>(qkv, vals);
    out_gemm<<<dim3(Mn / 64, En / 128), 256, 0, stream>>>(vals, Wp, bp, x, outp);
    ln_kernel<<<dim3(Mn), 256, 0, stream>>>(outp, gamma, beta, (float*)d_out);
}

// Round 6
// 211.597 us; speedup vs baseline: 11.1075x; 1.0514x over previous
//
#include <hip/hip_runtime.h>

// Problem constants
constexpr int Bn = 2;
constexpr int Sn = 2048;
constexpr int En = 512;
constexpr int Hn = 8;
constexpr int Dn = 64;
constexpr int Mn = Bn * Sn;              // 4096 rows

typedef short bf8 __attribute__((ext_vector_type(8)));
typedef float f32x4 __attribute__((ext_vector_type(4)));

// element counts (ushort units) for the bf16 workspace region
constexpr size_t XY = (size_t)Mn * En;          // 2,097,152  x planes
constexpr size_t WT = (size_t)3 * En * En;      //   786,432  Wqkv transposed planes
constexpr size_t WP = (size_t)En * En;          //   262,144  Wp planes
constexpr size_t PL = (size_t)Bn * Hn * Sn * Dn;// 2,097,152  q/k/v planes

__device__ __forceinline__ unsigned short f2bf(float f) {
    unsigned int u = __float_as_uint(f);
    unsigned int r = 0x7FFFu + ((u >> 16) & 1u);
    return (unsigned short)((u + r) >> 16);
}
__device__ __forceinline__ float bf2f(unsigned short u) {
    return __uint_as_float(((unsigned int)u) << 16);
}
__device__ __forceinline__ void split2(float f, unsigned short& hi, unsigned short& lo) {
    hi = f2bf(f);
    lo = f2bf(f - bf2f(hi));
}

// ---------------------------------------------------------------------------
// Prep A: row-major pre-split (x and Wp). 8 elements per thread.
// ---------------------------------------------------------------------------
__global__ __launch_bounds__(256)
void presplit(const float* __restrict__ src,
              unsigned short* __restrict__ hi_p,
              unsigned short* __restrict__ lo_p)
{
    const size_t base = ((size_t)blockIdx.x * 256 + threadIdx.x) * 8;
    float a[8];
    *(float4*)&a[0] = *(const float4*)(src + base);
    *(float4*)&a[4] = *(const float4*)(src + base + 4);
    unsigned short h[8], l[8];
    #pragma unroll
    for (int j = 0; j < 8; ++j) split2(a[j], h[j], l[j]);
    *(bf8*)(hi_p + base) = *(bf8*)&h[0];
    *(bf8*)(lo_p + base) = *(bf8*)&l[0];
}

// ---------------------------------------------------------------------------
// Prep B: transpose+split Wq/Wk/Wv [h][e][d] -> Wt[n=proj*512+h*64+d][k=e].
// One block per (proj*8+h, e-tile of 64); LDS 64x65 fp32 transpose.
// ---------------------------------------------------------------------------
__global__ __launch_bounds__(256)
void split_wt(const float* __restrict__ Wq,
              const float* __restrict__ Wk,
              const float* __restrict__ Wv,
              unsigned short* __restrict__ Wth,
              unsigned short* __restrict__ Wtl)
{
    __shared__ float t[64][65];
    const int ph = blockIdx.x;            // 0..23
    const int proj = ph >> 3, h = ph & 7;
    const int e0 = blockIdx.y * 64;
    const int tid = threadIdx.x;
    const float* W = (proj == 0) ? Wq : (proj == 1) ? Wk : Wv;
    const float* src = W + (size_t)h * En * Dn + (size_t)e0 * Dn;

    const int er = tid >> 2, cg = (tid & 3) * 16;
    #pragma unroll
    for (int c = 0; c < 4; ++c) {
        float4 v = *(const float4*)(src + (size_t)er * Dn + cg + 4 * c);
        t[er][cg + 4 * c + 0] = v.x;
        t[er][cg + 4 * c + 1] = v.y;
        t[er][cg + 4 * c + 2] = v.z;
        t[er][cg + 4 * c + 3] = v.w;
    }
    __syncthreads();

    const int d = tid >> 2, jg = (tid & 3) * 16;
    unsigned short h16[16], l16[16];
    #pragma unroll
    for (int j = 0; j < 16; ++j) split2(t[jg + j][d], h16[j], l16[j]);
    const size_t n = (size_t)proj * 512 + h * 64 + d;
    unsigned short* dh = Wth + n * En + e0 + jg;
    unsigned short* dl = Wtl + n * En + e0 + jg;
    *(bf8*)dh       = *(bf8*)&h16[0];
    *(bf8*)(dh + 8) = *(bf8*)&h16[8];
    *(bf8*)dl       = *(bf8*)&l16[0];
    *(bf8*)(dl + 8) = *(bf8*)&l16[8];
}

// ---------------------------------------------------------------------------
// Kernel 1 (v3): fused QKV projection, all-bf16 staging (pure copies).
// Outputs pre-split bf16: qh/ql/kh/kl [bh][s][d], V transposed vT [bh][d][s].
// ---------------------------------------------------------------------------
__global__ __launch_bounds__(256)
void qkv_gemm(const unsigned short* __restrict__ xh,
              const unsigned short* __restrict__ xl,
              const unsigned short* __restrict__ Wth,
              const unsigned short* __restrict__ Wtl,
              unsigned short* __restrict__ qh_g,
              unsigned short* __restrict__ ql_g,
              unsigned short* __restrict__ kh_g,
              unsigned short* __restrict__ kl_g,
              unsigned short* __restrict__ vT_g)
{
    __shared__ unsigned short Ah[128][40], Al[128][40];
    __shared__ unsigned short Bh[128][40], Bl[128][40];

    const int tid = threadIdx.x;
    const int m0 = blockIdx.x * 128;
    const int n0 = blockIdx.y * 128;      // global n in [0,1536)
    const int proj = n0 >> 9;
    const int within = n0 & 511;

    const int wave = tid >> 6, lane = tid & 63;
    const int wm = (wave >> 1) * 64, wn = (wave & 1) * 64;
    const int lm = lane & 15, quad = lane >> 4;

    const int am = tid >> 1;
    const int aks = (tid & 1) * 16;
    const unsigned short* arh = xh + (size_t)(m0 + am) * En + aks;
    const unsigned short* arl = xl + (size_t)(m0 + am) * En + aks;

    const int nn = tid & 127;
    const int bkg = (tid >> 7) * 16;
    const unsigned short* brh = Wth + (size_t)(n0 + nn) * En + bkg;
    const unsigned short* brl = Wtl + (size_t)(n0 + nn) * En + bkg;

    f32x4 acc[4][4];
    #pragma unroll
    for (int i = 0; i < 4; ++i)
        #pragma unroll
        for (int j = 0; j < 4; ++j) acc[i][j] = (f32x4){0.f, 0.f, 0.f, 0.f};

    for (int k0 = 0; k0 < En; k0 += 32) {
        *(bf8*)&Ah[am][aks]     = *(const bf8*)(arh + k0);
        *(bf8*)&Ah[am][aks + 8] = *(const bf8*)(arh + k0 + 8);
        *(bf8*)&Al[am][aks]     = *(const bf8*)(arl + k0);
        *(bf8*)&Al[am][aks + 8] = *(const bf8*)(arl + k0 + 8);
        *(bf8*)&Bh[nn][bkg]     = *(const bf8*)(brh + k0);
        *(bf8*)&Bh[nn][bkg + 8] = *(const bf8*)(brh + k0 + 8);
        *(bf8*)&Bl[nn][bkg]     = *(const bf8*)(brl + k0);
        *(bf8*)&Bl[nn][bkg + 8] = *(const bf8*)(brl + k0 + 8);
        __syncthreads();

        bf8 a_h[4], a_l[4], b_h[4], b_l[4];
        #pragma unroll
        for (int mi = 0; mi < 4; ++mi) {
            a_h[mi] = *(const bf8*)&Ah[wm + mi * 16 + lm][quad * 8];
            a_l[mi] = *(const bf8*)&Al[wm + mi * 16 + lm][quad * 8];
        }
        #pragma unroll
        for (int ni = 0; ni < 4; ++ni) {
            b_h[ni] = *(const bf8*)&Bh[wn + ni * 16 + lm][quad * 8];
            b_l[ni] = *(const bf8*)&Bl[wn + ni * 16 + lm][quad * 8];
        }
        #pragma unroll
        for (int mi = 0; mi < 4; ++mi)
            #pragma unroll
            for (int ni = 0; ni < 4; ++ni) {
                acc[mi][ni] = __builtin_amdgcn_mfma_f32_16x16x32_bf16(a_h[mi], b_h[ni], acc[mi][ni], 0, 0, 0);
                acc[mi][ni] = __builtin_amdgcn_mfma_f32_16x16x32_bf16(a_h[mi], b_l[ni], acc[mi][ni], 0, 0, 0);
                acc[mi][ni] = __builtin_amdgcn_mfma_f32_16x16x32_bf16(a_l[mi], b_h[ni], acc[mi][ni], 0, 0, 0);
            }
        __syncthreads();
    }

    // Epilogue. m -> (b,s); nl -> (h,d). proj is wave-uniform.
    if (proj < 2) {
        unsigned short* hp = (proj == 0) ? qh_g : kh_g;
        unsigned short* lp = (proj == 0) ? ql_g : kl_g;
        #pragma unroll
        for (int mi = 0; mi < 4; ++mi) {
            #pragma unroll
            for (int r = 0; r < 4; ++r) {
                const int m = m0 + wm + mi * 16 + quad * 4 + r;
                const int b = m >> 11, s = m & 2047;
                #pragma unroll
                for (int ni = 0; ni < 4; ++ni) {
                    const int nl = within + wn + ni * 16 + lm;
                    const int h = nl >> 6, d = nl & 63;
                    const size_t idx = (((size_t)(b * Hn + h) * Sn + s) * Dn) + d;
                    unsigned short hv, lv;
                    split2(acc[mi][ni][r], hv, lv);
                    hp[idx] = hv;
                    lp[idx] = lv;
                }
            }
        }
    } else {
        // V: transposed, pack 4 consecutive s per store
        #pragma unroll
        for (int mi = 0; mi < 4; ++mi) {
            const int s0 = m0 + wm + mi * 16 + quad * 4;
            const int b = s0 >> 11, s = s0 & 2047;
            #pragma unroll
            for (int ni = 0; ni < 4; ++ni) {
                const int nl = within + wn + ni * 16 + lm;
                const int h = nl >> 6, d = nl & 63;
                ushort4 pk;
                pk.x = f2bf(acc[mi][ni][0]);
                pk.y = f2bf(acc[mi][ni][1]);
                pk.z = f2bf(acc[mi][ni][2]);
                pk.w = f2bf(acc[mi][ni][3]);
                *(ushort4*)(vT_g + ((size_t)(b * Hn + h) * Dn + d) * Sn + s) = pk;
            }
        }
    }
}

// ---------------------------------------------------------------------------
// Kernel 2 (v4): MFMA flash attention, pre-split bf16 inputs.
// Q frags direct global->reg; K/V staging = raw bf8 copies. LDS 37.4 KB.
// ---------------------------------------------------------------------------
__global__ __launch_bounds__(256)
void attn(const unsigned short* __restrict__ qh_g,
          const unsigned short* __restrict__ ql_g,
          const unsigned short* __restrict__ kh_g,
          const unsigned short* __restrict__ kl_g,
          const unsigned short* __restrict__ vT_g,
          float* __restrict__ vals)
{
    extern __shared__ unsigned short sm[];
    unsigned short (*khs)[72] = (unsigned short(*)[72])(sm);          // [t][d] hi
    unsigned short (*kls)[72] = (unsigned short(*)[72])(sm + 4608);   // [t][d] lo
    unsigned short (*vTs)[72] = (unsigned short(*)[72])(sm + 9216);   // [d][t]
    unsigned short (*pts)[72] = (unsigned short(*)[72])(sm + 13824);  // [q][t]
    float* alf  = (float*)(sm + 18432);                               // [64]
    float* linv = alf + 64;                                           // [64]

    const int bidx = blockIdx.x;
    const int jj_ = bidx >> 4;
    const int bh = bidx & 15;
    const int qt = (jj_ < 16) ? jj_ : 47 - jj_;   // complementary pairing
    const int b = bh >> 3, h = bh & 7;
    const int tid = threadIdx.x;
    const int wave = tid >> 6, lane = tid & 63;
    const int quad = lane >> 4, lq = lane & 15;

    const unsigned short* khb = kh_g + (size_t)bh * Sn * Dn;
    const unsigned short* klb = kl_g + (size_t)bh * Sn * Dn;
    const unsigned short* vTb = vT_g + (size_t)bh * Dn * Sn;

    // Q fragments: direct global loads (B operand)
    bf8 qfh[2], qfl[2];
    {
        const size_t qoff = ((size_t)bh * Sn + (size_t)qt * 64 + wave * 16 + lq) * Dn;
        #pragma unroll
        for (int c = 0; c < 2; ++c) {
            qfh[c] = *(const bf8*)(qh_g + qoff + c * 32 + quad * 8);
            qfl[c] = *(const bf8*)(ql_g + qoff + c * 32 + quad * 8);
        }
    }

    f32x4 accO[4];
    #pragma unroll
    for (int nj = 0; nj < 4; ++nj) accO[nj] = (f32x4){0.f, 0.f, 0.f, 0.f};
    float m = -INFINITY, l = 0.f;

    const int srow = tid & 63;
    const int sdg  = tid >> 6;

    const int ntk = qt + 1;
    for (int it = 0; it < ntk; ++it) {
        const int t0 = it * 64;
        __syncthreads();   // prev tile fully consumed
        // stage K hi/lo rows + vT rows (raw copies)
        {
            const unsigned short* kr = khb + (size_t)(t0 + srow) * Dn + sdg * 16;
            const unsigned short* lr = klb + (size_t)(t0 + srow) * Dn + sdg * 16;
            const unsigned short* vr = vTb + (size_t)srow * Sn + t0 + sdg * 16;
            *(bf8*)&khs[srow][sdg * 16]     = *(const bf8*)(kr);
            *(bf8*)&khs[srow][sdg * 16 + 8] = *(const bf8*)(kr + 8);
            *(bf8*)&kls[srow][sdg * 16]     = *(const bf8*)(lr);
            *(bf8*)&kls[srow][sdg * 16 + 8] = *(const bf8*)(lr + 8);
            *(bf8*)&vTs[srow][sdg * 16]     = *(const bf8*)(vr);
            *(bf8*)&vTs[srow][sdg * 16 + 8] = *(const bf8*)(vr + 8);
        }
        __syncthreads();

        // scores: S^T = K Q^T (split-bf16, 3 MFMAs per chunk)
        f32x4 accS[4];
        #pragma unroll
        for (int mi = 0; mi < 4; ++mi) accS[mi] = (f32x4){0.f, 0.f, 0.f, 0.f};
        #pragma unroll
        for (int mi = 0; mi < 4; ++mi) {
            #pragma unroll
            for (int c = 0; c < 2; ++c) {
                bf8 ah = *(const bf8*)&khs[mi * 16 + lq][c * 32 + quad * 8];
                bf8 al = *(const bf8*)&kls[mi * 16 + lq][c * 32 + quad * 8];
                accS[mi] = __builtin_amdgcn_mfma_f32_16x16x32_bf16(ah, qfh[c], accS[mi], 0, 0, 0);
                accS[mi] = __builtin_amdgcn_mfma_f32_16x16x32_bf16(ah, qfl[c], accS[mi], 0, 0, 0);
                accS[mi] = __builtin_amdgcn_mfma_f32_16x16x32_bf16(al, qfh[c], accS[mi], 0, 0, 0);
            }
        }

        // causal mask (diagonal tile only)
        if (it == qt) {
            const int qrel = wave * 16 + lq;
            #pragma unroll
            for (int mi = 0; mi < 4; ++mi)
                #pragma unroll
                for (int r = 0; r < 4; ++r)
                    if (mi * 16 + quad * 4 + r > qrel) accS[mi][r] = -INFINITY;
        }

        // online softmax (per q = lane&15, replicated across quads)
        float mt = -INFINITY;
        #pragma unroll
        for (int mi = 0; mi < 4; ++mi)
            #pragma unroll
            for (int r = 0; r < 4; ++r) mt = fmaxf(mt, accS[mi][r]);
        mt = fmaxf(mt, __shfl_xor(mt, 16));
        mt = fmaxf(mt, __shfl_xor(mt, 32));
        const float mnew = fmaxf(m, mt);
        const float alpha = __expf(m - mnew);
        float ls = 0.f;
        #pragma unroll
        for (int mi = 0; mi < 4; ++mi)
            #pragma unroll
            for (int r = 0; r < 4; ++r) {
                const float p = __expf(accS[mi][r] - mnew);
                accS[mi][r] = p;
                ls += p;
            }
        ls += __shfl_xor(ls, 16);
        ls += __shfl_xor(ls, 32);
        l = l * alpha + ls;
        m = mnew;

        // P -> LDS (bf16, A-layout [q][t]); wave-local
        #pragma unroll
        for (int mi = 0; mi < 4; ++mi) {
            ushort4 pk;
            pk.x = f2bf(accS[mi][0]);
            pk.y = f2bf(accS[mi][1]);
            pk.z = f2bf(accS[mi][2]);
            pk.w = f2bf(accS[mi][3]);
            *(ushort4*)&pts[wave * 16 + lq][mi * 16 + quad * 4] = pk;
        }
        if (quad == 0) alf[wave * 16 + lq] = alpha;

        // O rescale + PV
        {
            float4 al4 = *(const float4*)&alf[wave * 16 + quad * 4];
            #pragma unroll
            for (int nj = 0; nj < 4; ++nj) {
                accO[nj][0] *= al4.x;
                accO[nj][1] *= al4.y;
                accO[nj][2] *= al4.z;
                accO[nj][3] *= al4.w;
            }
            #pragma unroll
            for (int c = 0; c < 2; ++c) {
                bf8 pf = *(const bf8*)&pts[wave * 16 + lq][c * 32 + quad * 8];
                #pragma unroll
                for (int nj = 0; nj < 4; ++nj) {
                    bf8 vf = *(const bf8*)&vTs[nj * 16 + lq][c * 32 + quad * 8];
                    accO[nj] = __builtin_amdgcn_mfma_f32_16x16x32_bf16(pf, vf, accO[nj], 0, 0, 0);
                }
            }
        }
    }

    if (quad == 0) linv[wave * 16 + lq] = 1.f / l;
    float4 li4 = *(const float4*)&linv[wave * 16 + quad * 4];
    const float lir[4] = {li4.x, li4.y, li4.z, li4.w};

    // epilogue: normalize + head-reversed write
    #pragma unroll
    for (int r = 0; r < 4; ++r) {
        const int s = qt * 64 + wave * 16 + quad * 4 + r;
        float* dst = vals + ((size_t)(b * Sn + s)) * En + (size_t)(7 - h) * 64;
        #pragma unroll
        for (int nj = 0; nj < 4; ++nj)
            dst[nj * 16 + lq] = accO[nj][r] * lir[r];
    }
}

// ---------------------------------------------------------------------------
// Kernel 3 (v3): out = vals @ Wp^T + bp + x; Wp pre-split (copies), A split2.
// ---------------------------------------------------------------------------
__global__ __launch_bounds__(256)
void out_gemm(const float* __restrict__ vals,
              const unsigned short* __restrict__ Wph,
              const unsigned short* __restrict__ Wpl,
              const float* __restrict__ bp,
              const float* __restrict__ x,
              float* __restrict__ outp)
{
    __shared__ unsigned short Ah[64][40], Al[64][40];
    __shared__ unsigned short Bh[128][40], Bl[128][40];

    const int tid = threadIdx.x;
    const int m0 = blockIdx.x * 64;
    const int n0 = blockIdx.y * 128;

    const int wave = tid >> 6, lane = tid & 63;
    const int wm = (wave >> 1) * 32, wn = (wave & 1) * 64;
    const int lm = lane & 15, quad = lane >> 4;

    const int am = tid >> 2;
    const int aks = (tid & 3) * 8;
    const float* arow = vals + (size_t)(m0 + am) * En + aks;

    const int bn = tid >> 1;
    const int bks = (tid & 1) * 16;
    const unsigned short* brh = Wph + (size_t)(n0 + bn) * En + bks;
    const unsigned short* brl = Wpl + (size_t)(n0 + bn) * En + bks;

    f32x4 acc[2][4];
    #pragma unroll
    for (int i = 0; i < 2; ++i)
        #pragma unroll
        for (int j = 0; j < 4; ++j) acc[i][j] = (f32x4){0.f, 0.f, 0.f, 0.f};

    for (int k0 = 0; k0 < En; k0 += 32) {
        {
            float av[8];
            *(float4*)&av[0] = *(const float4*)(arow + k0);
            *(float4*)&av[4] = *(const float4*)(arow + k0 + 4);
            unsigned short hi[8], lo[8];
            #pragma unroll
            for (int j = 0; j < 8; ++j) split2(av[j], hi[j], lo[j]);
            *(bf8*)&Ah[am][aks] = *(bf8*)&hi[0];
            *(bf8*)&Al[am][aks] = *(bf8*)&lo[0];
        }
        *(bf8*)&Bh[bn][bks]     = *(const bf8*)(brh + k0);
        *(bf8*)&Bh[bn][bks + 8] = *(const bf8*)(brh + k0 + 8);
        *(bf8*)&Bl[bn][bks]     = *(const bf8*)(brl + k0);
        *(bf8*)&Bl[bn][bks + 8] = *(const bf8*)(brl + k0 + 8);
        __syncthreads();

        bf8 a_h[2], a_l[2], b_h[4], b_l[4];
        #pragma unroll
        for (int mi = 0; mi < 2; ++mi) {
            a_h[mi] = *(const bf8*)&Ah[wm + mi * 16 + lm][quad * 8];
            a_l[mi] = *(const bf8*)&Al[wm + mi * 16 + lm][quad * 8];
        }
        #pragma unroll
        for (int ni = 0; ni < 4; ++ni) {
            b_h[ni] = *(const bf8*)&Bh[wn + ni * 16 + lm][quad * 8];
            b_l[ni] = *(const bf8*)&Bl[wn + ni * 16 + lm][quad * 8];
        }
        #pragma unroll
        for (int mi = 0; mi < 2; ++mi)
            #pragma unroll
            for (int ni = 0; ni < 4; ++ni) {
                acc[mi][ni] = __builtin_amdgcn_mfma_f32_16x16x32_bf16(a_h[mi], b_h[ni], acc[mi][ni], 0, 0, 0);
                acc[mi][ni] = __builtin_amdgcn_mfma_f32_16x16x32_bf16(a_h[mi], b_l[ni], acc[mi][ni], 0, 0, 0);
                acc[mi][ni] = __builtin_amdgcn_mfma_f32_16x16x32_bf16(a_l[mi], b_h[ni], acc[mi][ni], 0, 0, 0);
            }
        __syncthreads();
    }

    #pragma unroll
    for (int mi = 0; mi < 2; ++mi) {
        #pragma unroll
        for (int r = 0; r < 4; ++r) {
            const int m = m0 + wm + mi * 16 + quad * 4 + r;
            #pragma unroll
            for (int ni = 0; ni < 4; ++ni) {
                const int n = n0 + wn + ni * 16 + lm;
                const size_t idx = (size_t)m * En + n;
                outp[idx] = acc[mi][ni][r] + bp[n] + x[idx];
            }
        }
    }
}

// ---------------------------------------------------------------------------
// Kernel 4: row-wise LayerNorm (unchanged).
// ---------------------------------------------------------------------------
__global__ __launch_bounds__(256)
void ln_kernel(const float* __restrict__ outp,
               const float* __restrict__ gamma,
               const float* __restrict__ beta,
               float* __restrict__ y)
{
    const int row = blockIdx.x;
    const int tid = threadIdx.x;
    const float* r = outp + (size_t)row * En;

    const float a = r[tid];
    const float b = r[tid + 256];
    float sum = a + b;
    float sq = a * a + b * b;
    #pragma unroll
    for (int off = 32; off > 0; off >>= 1) {
        sum += __shfl_down(sum, off);
        sq  += __shfl_down(sq, off);
    }
    __shared__ float ls[4], lq[4];
    const int wid = tid >> 6, lane = tid & 63;
    if (lane == 0) { ls[wid] = sum; lq[wid] = sq; }
    __syncthreads();
    if (tid == 0) {
        float S = 0.f, Q = 0.f;
        #pragma unroll
        for (int w = 0; w < 4; ++w) { S += ls[w]; Q += lq[w]; }
        ls[0] = S; lq[0] = Q;
    }
    __syncthreads();
    const float mu = ls[0] * (1.f / 512.f);
    const float var = lq[0] * (1.f / 512.f) - mu * mu;
    const float rs = rsqrtf(var + 1e-5f);

    float* yr = y + (size_t)row * En;
    yr[tid]       = (a - mu) * rs * gamma[tid]       + beta[tid];
    yr[tid + 256] = (b - mu) * rs * gamma[tid + 256] + beta[tid + 256];
}

// ---------------------------------------------------------------------------
extern "C" void kernel_launch(void* const* d_in, const int* in_sizes, int n_in,
                              void* d_out, int out_size, void* d_ws, size_t ws_size,
                              hipStream_t stream)
{
    const float* x     = (const float*)d_in[0];
    const float* Wq    = (const float*)d_in[1];
    const float* Wk    = (const float*)d_in[2];
    const float* Wv    = (const float*)d_in[3];
    const float* Wp    = (const float*)d_in[4];
    const float* bp    = (const float*)d_in[5];
    const float* gamma = (const float*)d_in[6];
    const float* beta  = (const float*)d_in[7];
    // d_in[8] = mask (int32 tril) — causal, applied analytically.

    float* ws   = (float*)d_ws;
    float* vals = ws;                            // 2M floats (8 MB)
    float* outp = ws + XY;                       // 2M floats (8 MB)
    unsigned short* bfb = (unsigned short*)(ws + 2 * XY);
    unsigned short* xh  = bfb;
    unsigned short* xl  = bfb + XY;
    unsigned short* Wth = bfb + 2 * XY;
    unsigned short* Wtl = Wth + WT;
    unsigned short* Wph = Wtl + WT;
    unsigned short* Wpl = Wph + WP;
    unsigned short* qh  = Wpl + WP;
    unsigned short* ql  = qh + PL;
    unsigned short* kh  = ql + PL;
    unsigned short* kl  = kh + PL;
    unsigned short* vT  = kl + PL;

    const int attn_lds = 18432 * 2 + 512;        // 37,376 B
    hipFuncSetAttribute((const void*)attn,
                        hipFuncAttributeMaxDynamicSharedMemorySize, attn_lds);

    presplit<<<dim3((int)(XY / (256 * 8))), 256, 0, stream>>>(x, xh, xl);
    presplit<<<dim3((int)(WP / (256 * 8))), 256, 0, stream>>>(Wp, Wph, Wpl);
    split_wt<<<dim3(24, 8), 256, 0, stream>>>(Wq, Wk, Wv, Wth, Wtl);
    qkv_gemm<<<dim3(Mn / 128, 12), 256, 0, stream>>>(xh, xl, Wth, Wtl,
                                                     qh, ql, kh, kl, vT);
    attn<<<dim3(512), 256, attn_lds, stream>>>(qh, ql, kh, kl, vT, vals);
    out_gemm<<<dim3(Mn / 64, En / 128), 256, 0, stream>>>(vals, Wph, Wpl, bp, x, outp);
    ln_kernel<<<dim3(Mn), 256, 0, stream>>>(outp, gamma, beta, (float*)d_out);
}

// Round 7
// 184.464 us; speedup vs baseline: 12.7414x; 1.1471x over previous
//
#include <hip/hip_runtime.h>

// Problem constants
constexpr int Bn = 2;
constexpr int Sn = 2048;
constexpr int En = 512;
constexpr int Hn = 8;
constexpr int Dn = 64;
constexpr int Mn = Bn * Sn;              // 4096 rows

typedef short bf8 __attribute__((ext_vector_type(8)));
typedef float f32x4 __attribute__((ext_vector_type(4)));

// element counts (ushort units) for the bf16 workspace region
constexpr size_t XY = (size_t)Mn * En;          // 2,097,152  x planes
constexpr size_t WT = (size_t)3 * En * En;      //   786,432  Wqkv transposed planes
constexpr size_t WP = (size_t)En * En;          //   262,144  Wp planes
constexpr size_t PL = (size_t)Bn * Hn * Sn * Dn;// 2,097,152  q/k/v planes

__device__ __forceinline__ unsigned short f2bf(float f) {
    unsigned int u = __float_as_uint(f);
    unsigned int r = 0x7FFFu + ((u >> 16) & 1u);
    return (unsigned short)((u + r) >> 16);
}
__device__ __forceinline__ float bf2f(unsigned short u) {
    return __uint_as_float(((unsigned int)u) << 16);
}
__device__ __forceinline__ void split2(float f, unsigned short& hi, unsigned short& lo) {
    hi = f2bf(f);
    lo = f2bf(f - bf2f(hi));
}

// ---------------------------------------------------------------------------
// Prep (fused): blocks [0,1024) presplit x; [1024,1152) presplit Wp;
// [1152,1344) transpose+split Wq/Wk/Wv -> Wt[n][k].
// ---------------------------------------------------------------------------
__global__ __launch_bounds__(256)
void prep(const float* __restrict__ x, const float* __restrict__ Wp,
          const float* __restrict__ Wq, const float* __restrict__ Wk,
          const float* __restrict__ Wv,
          unsigned short* __restrict__ xh, unsigned short* __restrict__ xl,
          unsigned short* __restrict__ Wph, unsigned short* __restrict__ Wpl,
          unsigned short* __restrict__ Wth, unsigned short* __restrict__ Wtl)
{
    __shared__ float t[64][65];
    const int bid = blockIdx.x;
    const int tid = threadIdx.x;

    if (bid < 1152) {
        const float* src = (bid < 1024) ? x : Wp;
        unsigned short* hp = (bid < 1024) ? xh : Wph;
        unsigned short* lp = (bid < 1024) ? xl : Wpl;
        const int blk = (bid < 1024) ? bid : (bid - 1024);
        const size_t base = ((size_t)blk * 256 + tid) * 8;
        float a[8];
        *(float4*)&a[0] = *(const float4*)(src + base);
        *(float4*)&a[4] = *(const float4*)(src + base + 4);
        unsigned short h[8], l[8];
        #pragma unroll
        for (int j = 0; j < 8; ++j) split2(a[j], h[j], l[j]);
        *(bf8*)(hp + base) = *(bf8*)&h[0];
        *(bf8*)(lp + base) = *(bf8*)&l[0];
        return;
    }

    const int idx = bid - 1152;           // 0..191
    const int ph = idx >> 3;              // 0..23
    const int proj = ph >> 3, h = ph & 7;
    const int e0 = (idx & 7) * 64;
    const float* W = (proj == 0) ? Wq : (proj == 1) ? Wk : Wv;
    const float* src = W + (size_t)h * En * Dn + (size_t)e0 * Dn;

    const int er = tid >> 2, cg = (tid & 3) * 16;
    #pragma unroll
    for (int c = 0; c < 4; ++c) {
        float4 v = *(const float4*)(src + (size_t)er * Dn + cg + 4 * c);
        t[er][cg + 4 * c + 0] = v.x;
        t[er][cg + 4 * c + 1] = v.y;
        t[er][cg + 4 * c + 2] = v.z;
        t[er][cg + 4 * c + 3] = v.w;
    }
    __syncthreads();

    const int d = tid >> 2, jg = (tid & 3) * 16;
    unsigned short h16[16], l16[16];
    #pragma unroll
    for (int j = 0; j < 16; ++j) split2(t[jg + j][d], h16[j], l16[j]);
    const size_t n = (size_t)proj * 512 + h * 64 + d;
    unsigned short* dh = Wth + n * En + e0 + jg;
    unsigned short* dl = Wtl + n * En + e0 + jg;
    *(bf8*)dh       = *(bf8*)&h16[0];
    *(bf8*)(dh + 8) = *(bf8*)&h16[8];
    *(bf8*)dl       = *(bf8*)&l16[0];
    *(bf8*)(dl + 8) = *(bf8*)&l16[8];
}

// ---------------------------------------------------------------------------
// Kernel 1: fused QKV projection, all-bf16 staging (unchanged from R6).
// ---------------------------------------------------------------------------
__global__ __launch_bounds__(256)
void qkv_gemm(const unsigned short* __restrict__ xh,
              const unsigned short* __restrict__ xl,
              const unsigned short* __restrict__ Wth,
              const unsigned short* __restrict__ Wtl,
              unsigned short* __restrict__ qh_g,
              unsigned short* __restrict__ ql_g,
              unsigned short* __restrict__ kh_g,
              unsigned short* __restrict__ kl_g,
              unsigned short* __restrict__ vT_g)
{
    __shared__ unsigned short Ah[128][40], Al[128][40];
    __shared__ unsigned short Bh[128][40], Bl[128][40];

    const int tid = threadIdx.x;
    const int m0 = blockIdx.x * 128;
    const int n0 = blockIdx.y * 128;
    const int proj = n0 >> 9;
    const int within = n0 & 511;

    const int wave = tid >> 6, lane = tid & 63;
    const int wm = (wave >> 1) * 64, wn = (wave & 1) * 64;
    const int lm = lane & 15, quad = lane >> 4;

    const int am = tid >> 1;
    const int aks = (tid & 1) * 16;
    const unsigned short* arh = xh + (size_t)(m0 + am) * En + aks;
    const unsigned short* arl = xl + (size_t)(m0 + am) * En + aks;

    const int nn = tid & 127;
    const int bkg = (tid >> 7) * 16;
    const unsigned short* brh = Wth + (size_t)(n0 + nn) * En + bkg;
    const unsigned short* brl = Wtl + (size_t)(n0 + nn) * En + bkg;

    f32x4 acc[4][4];
    #pragma unroll
    for (int i = 0; i < 4; ++i)
        #pragma unroll
        for (int j = 0; j < 4; ++j) acc[i][j] = (f32x4){0.f, 0.f, 0.f, 0.f};

    for (int k0 = 0; k0 < En; k0 += 32) {
        *(bf8*)&Ah[am][aks]     = *(const bf8*)(arh + k0);
        *(bf8*)&Ah[am][aks + 8] = *(const bf8*)(arh + k0 + 8);
        *(bf8*)&Al[am][aks]     = *(const bf8*)(arl + k0);
        *(bf8*)&Al[am][aks + 8] = *(const bf8*)(arl + k0 + 8);
        *(bf8*)&Bh[nn][bkg]     = *(const bf8*)(brh + k0);
        *(bf8*)&Bh[nn][bkg + 8] = *(const bf8*)(brh + k0 + 8);
        *(bf8*)&Bl[nn][bkg]     = *(const bf8*)(brl + k0);
        *(bf8*)&Bl[nn][bkg + 8] = *(const bf8*)(brl + k0 + 8);
        __syncthreads();

        bf8 a_h[4], a_l[4], b_h[4], b_l[4];
        #pragma unroll
        for (int mi = 0; mi < 4; ++mi) {
            a_h[mi] = *(const bf8*)&Ah[wm + mi * 16 + lm][quad * 8];
            a_l[mi] = *(const bf8*)&Al[wm + mi * 16 + lm][quad * 8];
        }
        #pragma unroll
        for (int ni = 0; ni < 4; ++ni) {
            b_h[ni] = *(const bf8*)&Bh[wn + ni * 16 + lm][quad * 8];
            b_l[ni] = *(const bf8*)&Bl[wn + ni * 16 + lm][quad * 8];
        }
        #pragma unroll
        for (int mi = 0; mi < 4; ++mi)
            #pragma unroll
            for (int ni = 0; ni < 4; ++ni) {
                acc[mi][ni] = __builtin_amdgcn_mfma_f32_16x16x32_bf16(a_h[mi], b_h[ni], acc[mi][ni], 0, 0, 0);
                acc[mi][ni] = __builtin_amdgcn_mfma_f32_16x16x32_bf16(a_h[mi], b_l[ni], acc[mi][ni], 0, 0, 0);
                acc[mi][ni] = __builtin_amdgcn_mfma_f32_16x16x32_bf16(a_l[mi], b_h[ni], acc[mi][ni], 0, 0, 0);
            }
        __syncthreads();
    }

    if (proj < 2) {
        unsigned short* hp = (proj == 0) ? qh_g : kh_g;
        unsigned short* lp = (proj == 0) ? ql_g : kl_g;
        #pragma unroll
        for (int mi = 0; mi < 4; ++mi) {
            #pragma unroll
            for (int r = 0; r < 4; ++r) {
                const int m = m0 + wm + mi * 16 + quad * 4 + r;
                const int b = m >> 11, s = m & 2047;
                #pragma unroll
                for (int ni = 0; ni < 4; ++ni) {
                    const int nl = within + wn + ni * 16 + lm;
                    const int h = nl >> 6, d = nl & 63;
                    const size_t idx = (((size_t)(b * Hn + h) * Sn + s) * Dn) + d;
                    unsigned short hv, lv;
                    split2(acc[mi][ni][r], hv, lv);
                    hp[idx] = hv;
                    lp[idx] = lv;
                }
            }
        }
    } else {
        #pragma unroll
        for (int mi = 0; mi < 4; ++mi) {
            const int s0 = m0 + wm + mi * 16 + quad * 4;
            const int b = s0 >> 11, s = s0 & 2047;
            #pragma unroll
            for (int ni = 0; ni < 4; ++ni) {
                const int nl = within + wn + ni * 16 + lm;
                const int h = nl >> 6, d = nl & 63;
                ushort4 pk;
                pk.x = f2bf(acc[mi][ni][0]);
                pk.y = f2bf(acc[mi][ni][1]);
                pk.z = f2bf(acc[mi][ni][2]);
                pk.w = f2bf(acc[mi][ni][3]);
                *(ushort4*)(vT_g + ((size_t)(b * Hn + h) * Dn + d) * Sn + s) = pk;
            }
        }
    }
}

// ---------------------------------------------------------------------------
// Kernel 2 (v5): MFMA flash attention, split-t (2 halves per (bh,qt)).
// 1024 blocks -> 4 blocks/CU. Complementary mapping: CU's 4 blocks sum ~33
// tiles. Register prefetch of next K/V tile hides L2 latency under compute.
// Partials: O (bf16, pre-normalization) + m,l (fp32) -> combiner kernel.
// ---------------------------------------------------------------------------
__global__ __launch_bounds__(256)
void attn(const unsigned short* __restrict__ qh_g,
          const unsigned short* __restrict__ ql_g,
          const unsigned short* __restrict__ kh_g,
          const unsigned short* __restrict__ kl_g,
          const unsigned short* __restrict__ vT_g,
          unsigned short* __restrict__ Op,
          float* __restrict__ ml)
{
    extern __shared__ unsigned short sm[];
    unsigned short (*khs)[72] = (unsigned short(*)[72])(sm);          // [t][d] hi
    unsigned short (*kls)[72] = (unsigned short(*)[72])(sm + 4608);   // [t][d] lo
    unsigned short (*vTs)[72] = (unsigned short(*)[72])(sm + 9216);   // [d][t]
    unsigned short (*pts)[72] = (unsigned short(*)[72])(sm + 13824);  // [q][t]
    float* alf = (float*)(sm + 18432);                                // [64]

    const int bidx = blockIdx.x;
    const int r_ = bidx & 255, quarter = bidx >> 8;
    const int a_ = r_ >> 4, bh = r_ & 15;
    const int qt = (quarter & 1) ? (31 - a_) : a_;
    const int hf = quarter >> 1;
    const int n0 = (qt + 2) >> 1;
    const int its = hf ? n0 : 0;
    const int ite = hf ? (qt + 1) : n0;
    const int pslot = hf * 512 + bh * 32 + qt;

    const int tid = threadIdx.x;
    const int wave = tid >> 6, lane = tid & 63;
    const int quad = lane >> 4, lq = lane & 15;

    const unsigned short* khb = kh_g + (size_t)bh * Sn * Dn;
    const unsigned short* klb = kl_g + (size_t)bh * Sn * Dn;
    const unsigned short* vTb = vT_g + (size_t)bh * Dn * Sn;

    // Q fragments: direct global loads (B operand)
    bf8 qfh[2], qfl[2];
    {
        const size_t qoff = ((size_t)bh * Sn + (size_t)qt * 64 + wave * 16 + lq) * Dn;
        #pragma unroll
        for (int c = 0; c < 2; ++c) {
            qfh[c] = *(const bf8*)(qh_g + qoff + c * 32 + quad * 8);
            qfl[c] = *(const bf8*)(ql_g + qoff + c * 32 + quad * 8);
        }
    }

    f32x4 accO[4];
    #pragma unroll
    for (int nj = 0; nj < 4; ++nj) accO[nj] = (f32x4){0.f, 0.f, 0.f, 0.f};
    float m = -1e30f, l = 0.f;

    const int srow = tid & 63;
    const int sdg  = tid >> 6;

    bf8 pk0, pk1, pl0, pl1, pv0, pv1;     // prefetch registers
    if (its < ite) {
        const int t0 = its * 64;
        const unsigned short* kr = khb + (size_t)(t0 + srow) * Dn + sdg * 16;
        const unsigned short* lr = klb + (size_t)(t0 + srow) * Dn + sdg * 16;
        const unsigned short* vr = vTb + (size_t)srow * Sn + t0 + sdg * 16;
        pk0 = *(const bf8*)(kr);  pk1 = *(const bf8*)(kr + 8);
        pl0 = *(const bf8*)(lr);  pl1 = *(const bf8*)(lr + 8);
        pv0 = *(const bf8*)(vr);  pv1 = *(const bf8*)(vr + 8);
    }

    for (int it = its; it < ite; ++it) {
        __syncthreads();   // prev tile fully consumed
        *(bf8*)&khs[srow][sdg * 16]     = pk0;
        *(bf8*)&khs[srow][sdg * 16 + 8] = pk1;
        *(bf8*)&kls[srow][sdg * 16]     = pl0;
        *(bf8*)&kls[srow][sdg * 16 + 8] = pl1;
        *(bf8*)&vTs[srow][sdg * 16]     = pv0;
        *(bf8*)&vTs[srow][sdg * 16 + 8] = pv1;
        __syncthreads();

        if (it + 1 < ite) {   // prefetch next tile; completes under compute
            const int t1 = (it + 1) * 64;
            const unsigned short* kr = khb + (size_t)(t1 + srow) * Dn + sdg * 16;
            const unsigned short* lr = klb + (size_t)(t1 + srow) * Dn + sdg * 16;
            const unsigned short* vr = vTb + (size_t)srow * Sn + t1 + sdg * 16;
            pk0 = *(const bf8*)(kr);  pk1 = *(const bf8*)(kr + 8);
            pl0 = *(const bf8*)(lr);  pl1 = *(const bf8*)(lr + 8);
            pv0 = *(const bf8*)(vr);  pv1 = *(const bf8*)(vr + 8);
        }

        // scores: S^T = K Q^T (split-bf16, 3 MFMAs per chunk)
        f32x4 accS[4];
        #pragma unroll
        for (int mi = 0; mi < 4; ++mi) accS[mi] = (f32x4){0.f, 0.f, 0.f, 0.f};
        #pragma unroll
        for (int mi = 0; mi < 4; ++mi) {
            #pragma unroll
            for (int c = 0; c < 2; ++c) {
                bf8 ah = *(const bf8*)&khs[mi * 16 + lq][c * 32 + quad * 8];
                bf8 al = *(const bf8*)&kls[mi * 16 + lq][c * 32 + quad * 8];
                accS[mi] = __builtin_amdgcn_mfma_f32_16x16x32_bf16(ah, qfh[c], accS[mi], 0, 0, 0);
                accS[mi] = __builtin_amdgcn_mfma_f32_16x16x32_bf16(ah, qfl[c], accS[mi], 0, 0, 0);
                accS[mi] = __builtin_amdgcn_mfma_f32_16x16x32_bf16(al, qfh[c], accS[mi], 0, 0, 0);
            }
        }

        // causal mask (diagonal tile only)
        if (it == qt) {
            const int qrel = wave * 16 + lq;
            #pragma unroll
            for (int mi = 0; mi < 4; ++mi)
                #pragma unroll
                for (int r = 0; r < 4; ++r)
                    if (mi * 16 + quad * 4 + r > qrel) accS[mi][r] = -INFINITY;
        }

        // online softmax (per q = lane&15, replicated across quads)
        float mt = -INFINITY;
        #pragma unroll
        for (int mi = 0; mi < 4; ++mi)
            #pragma unroll
            for (int r = 0; r < 4; ++r) mt = fmaxf(mt, accS[mi][r]);
        mt = fmaxf(mt, __shfl_xor(mt, 16));
        mt = fmaxf(mt, __shfl_xor(mt, 32));
        const float mnew = fmaxf(m, mt);
        const float alpha = __expf(m - mnew);
        float ls = 0.f;
        #pragma unroll
        for (int mi = 0; mi < 4; ++mi)
            #pragma unroll
            for (int r = 0; r < 4; ++r) {
                const float p = __expf(accS[mi][r] - mnew);
                accS[mi][r] = p;
                ls += p;
            }
        ls += __shfl_xor(ls, 16);
        ls += __shfl_xor(ls, 32);
        l = l * alpha + ls;
        m = mnew;

        // P -> LDS (bf16, A-layout [q][t]); wave-local, no barrier needed
        #pragma unroll
        for (int mi = 0; mi < 4; ++mi) {
            ushort4 pk;
            pk.x = f2bf(accS[mi][0]);
            pk.y = f2bf(accS[mi][1]);
            pk.z = f2bf(accS[mi][2]);
            pk.w = f2bf(accS[mi][3]);
            *(ushort4*)&pts[wave * 16 + lq][mi * 16 + quad * 4] = pk;
        }
        if (quad == 0) alf[wave * 16 + lq] = alpha;

        // O rescale + PV
        {
            float4 al4 = *(const float4*)&alf[wave * 16 + quad * 4];
            #pragma unroll
            for (int nj = 0; nj < 4; ++nj) {
                accO[nj][0] *= al4.x;
                accO[nj][1] *= al4.y;
                accO[nj][2] *= al4.z;
                accO[nj][3] *= al4.w;
            }
            #pragma unroll
            for (int c = 0; c < 2; ++c) {
                bf8 pf = *(const bf8*)&pts[wave * 16 + lq][c * 32 + quad * 8];
                #pragma unroll
                for (int nj = 0; nj < 4; ++nj) {
                    bf8 vf = *(const bf8*)&vTs[nj * 16 + lq][c * 32 + quad * 8];
                    accO[nj] = __builtin_amdgcn_mfma_f32_16x16x32_bf16(pf, vf, accO[nj], 0, 0, 0);
                }
            }
        }
    }

    // partial epilogue: raw O (bf16) + m,l
    if (quad == 0) {
        const size_t mi_ = ((size_t)pslot * 64 + wave * 16 + lq) * 2;
        ml[mi_]     = m;
        ml[mi_ + 1] = l;
    }
    #pragma unroll
    for (int r = 0; r < 4; ++r) {
        const int q = wave * 16 + quad * 4 + r;
        unsigned short* dst = Op + ((size_t)pslot * 64 + q) * 64;
        #pragma unroll
        for (int nj = 0; nj < 4; ++nj)
            dst[nj * 16 + lq] = f2bf(accO[nj][r]);
    }
}

// ---------------------------------------------------------------------------
// Kernel 2b: flash-combine two halves, normalize, head-reversed write.
// 512 blocks = (bh, qt); thread t -> q = t>>2, d-group = (t&3)*16.
// ---------------------------------------------------------------------------
__global__ __launch_bounds__(256)
void attn_combine(const unsigned short* __restrict__ Op,
                  const float* __restrict__ ml,
                  float* __restrict__ vals)
{
    const int bq = blockIdx.x;            // bh*32 + qt
    const int bh = bq >> 5, qt = bq & 31;
    const int b = bh >> 3, h = bh & 7;
    const int t = threadIdx.x;
    const int q = t >> 2, dg = (t & 3) * 16;

    const size_t p0 = (size_t)bq * 64 + q;
    const size_t p1 = (size_t)(512 + bq) * 64 + q;
    const float m0 = ml[p0 * 2], l0 = ml[p0 * 2 + 1];
    const float m1 = ml[p1 * 2], l1 = ml[p1 * 2 + 1];
    const float mn = fmaxf(m0, m1);
    const float a0 = __expf(m0 - mn), a1 = __expf(m1 - mn);
    const float inv = 1.f / (a0 * l0 + a1 * l1);

    unsigned short o0[16], o1[16];
    *(bf8*)&o0[0] = *(const bf8*)(Op + p0 * 64 + dg);
    *(bf8*)&o0[8] = *(const bf8*)(Op + p0 * 64 + dg + 8);
    *(bf8*)&o1[0] = *(const bf8*)(Op + p1 * 64 + dg);
    *(bf8*)&o1[8] = *(const bf8*)(Op + p1 * 64 + dg + 8);

    float out[16];
    #pragma unroll
    for (int j = 0; j < 16; ++j)
        out[j] = (a0 * bf2f(o0[j]) + a1 * bf2f(o1[j])) * inv;

    float* dst = vals + ((size_t)(b * Sn + qt * 64 + q)) * En
                 + (size_t)(7 - h) * 64 + dg;
    *(float4*)(dst)      = *(float4*)&out[0];
    *(float4*)(dst + 4)  = *(float4*)&out[4];
    *(float4*)(dst + 8)  = *(float4*)&out[8];
    *(float4*)(dst + 12) = *(float4*)&out[12];
}

// ---------------------------------------------------------------------------
// Kernel 3: out = vals @ Wp^T + bp + x (unchanged from R6).
// ---------------------------------------------------------------------------
__global__ __launch_bounds__(256)
void out_gemm(const float* __restrict__ vals,
              const unsigned short* __restrict__ Wph,
              const unsigned short* __restrict__ Wpl,
              const float* __restrict__ bp,
              const float* __restrict__ x,
              float* __restrict__ outp)
{
    __shared__ unsigned short Ah[64][40], Al[64][40];
    __shared__ unsigned short Bh[128][40], Bl[128][40];

    const int tid = threadIdx.x;
    const int m0 = blockIdx.x * 64;
    const int n0 = blockIdx.y * 128;

    const int wave = tid >> 6, lane = tid & 63;
    const int wm = (wave >> 1) * 32, wn = (wave & 1) * 64;
    const int lm = lane & 15, quad = lane >> 4;

    const int am = tid >> 2;
    const int aks = (tid & 3) * 8;
    const float* arow = vals + (size_t)(m0 + am) * En + aks;

    const int bn = tid >> 1;
    const int bks = (tid & 1) * 16;
    const unsigned short* brh = Wph + (size_t)(n0 + bn) * En + bks;
    const unsigned short* brl = Wpl + (size_t)(n0 + bn) * En + bks;

    f32x4 acc[2][4];
    #pragma unroll
    for (int i = 0; i < 2; ++i)
        #pragma unroll
        for (int j = 0; j < 4; ++j) acc[i][j] = (f32x4){0.f, 0.f, 0.f, 0.f};

    for (int k0 = 0; k0 < En; k0 += 32) {
        {
            float av[8];
            *(float4*)&av[0] = *(const float4*)(arow + k0);
            *(float4*)&av[4] = *(const float4*)(arow + k0 + 4);
            unsigned short hi[8], lo[8];
            #pragma unroll
            for (int j = 0; j < 8; ++j) split2(av[j], hi[j], lo[j]);
            *(bf8*)&Ah[am][aks] = *(bf8*)&hi[0];
            *(bf8*)&Al[am][aks] = *(bf8*)&lo[0];
        }
        *(bf8*)&Bh[bn][bks]     = *(const bf8*)(brh + k0);
        *(bf8*)&Bh[bn][bks + 8] = *(const bf8*)(brh + k0 + 8);
        *(bf8*)&Bl[bn][bks]     = *(const bf8*)(brl + k0);
        *(bf8*)&Bl[bn][bks + 8] = *(const bf8*)(brl + k0 + 8);
        __syncthreads();

        bf8 a_h[2], a_l[2], b_h[4], b_l[4];
        #pragma unroll
        for (int mi = 0; mi < 2; ++mi) {
            a_h[mi] = *(const bf8*)&Ah[wm + mi * 16 + lm][quad * 8];
            a_l[mi] = *(const bf8*)&Al[wm + mi * 16 + lm][quad * 8];
        }
        #pragma unroll
        for (int ni = 0; ni < 4; ++ni) {
            b_h[ni] = *(const bf8*)&Bh[wn + ni * 16 + lm][quad * 8];
            b_l[ni] = *(const bf8*)&Bl[wn + ni * 16 + lm][quad * 8];
        }
        #pragma unroll
        for (int mi = 0; mi < 2; ++mi)
            #pragma unroll
            for (int ni = 0; ni < 4; ++ni) {
                acc[mi][ni] = __builtin_amdgcn_mfma_f32_16x16x32_bf16(a_h[mi], b_h[ni], acc[mi][ni], 0, 0, 0);
                acc[mi][ni] = __builtin_amdgcn_mfma_f32_16x16x32_bf16(a_h[mi], b_l[ni], acc[mi][ni], 0, 0, 0);
                acc[mi][ni] = __builtin_amdgcn_mfma_f32_16x16x32_bf16(a_l[mi], b_h[ni], acc[mi][ni], 0, 0, 0);
            }
        __syncthreads();
    }

    #pragma unroll
    for (int mi = 0; mi < 2; ++mi) {
        #pragma unroll
        for (int r = 0; r < 4; ++r) {
            const int m = m0 + wm + mi * 16 + quad * 4 + r;
            #pragma unroll
            for (int ni = 0; ni < 4; ++ni) {
                const int n = n0 + wn + ni * 16 + lm;
                const size_t idx = (size_t)m * En + n;
                outp[idx] = acc[mi][ni][r] + bp[n] + x[idx];
            }
        }
    }
}

// ---------------------------------------------------------------------------
// Kernel 4: row-wise LayerNorm (unchanged).
// ---------------------------------------------------------------------------
__global__ __launch_bounds__(256)
void ln_kernel(const float* __restrict__ outp,
               const float* __restrict__ gamma,
               const float* __restrict__ beta,
               float* __restrict__ y)
{
    const int row = blockIdx.x;
    const int tid = threadIdx.x;
    const float* r = outp + (size_t)row * En;

    const float a = r[tid];
    const float b = r[tid + 256];
    float sum = a + b;
    float sq = a * a + b * b;
    #pragma unroll
    for (int off = 32; off > 0; off >>= 1) {
        sum += __shfl_down(sum, off);
        sq  += __shfl_down(sq, off);
    }
    __shared__ float ls[4], lq[4];
    const int wid = tid >> 6, lane = tid & 63;
    if (lane == 0) { ls[wid] = sum; lq[wid] = sq; }
    __syncthreads();
    if (tid == 0) {
        float S = 0.f, Q = 0.f;
        #pragma unroll
        for (int w = 0; w < 4; ++w) { S += ls[w]; Q += lq[w]; }
        ls[0] = S; lq[0] = Q;
    }
    __syncthreads();
    const float mu = ls[0] * (1.f / 512.f);
    const float var = lq[0] * (1.f / 512.f) - mu * mu;
    const float rs = rsqrtf(var + 1e-5f);

    float* yr = y + (size_t)row * En;
    yr[tid]       = (a - mu) * rs * gamma[tid]       + beta[tid];
    yr[tid + 256] = (b - mu) * rs * gamma[tid + 256] + beta[tid + 256];
}

// ---------------------------------------------------------------------------
extern "C" void kernel_launch(void* const* d_in, const int* in_sizes, int n_in,
                              void* d_out, int out_size, void* d_ws, size_t ws_size,
                              hipStream_t stream)
{
    const float* x     = (const float*)d_in[0];
    const float* Wq    = (const float*)d_in[1];
    const float* Wk    = (const float*)d_in[2];
    const float* Wv    = (const float*)d_in[3];
    const float* Wp    = (const float*)d_in[4];
    const float* bp    = (const float*)d_in[5];
    const float* gamma = (const float*)d_in[6];
    const float* beta  = (const float*)d_in[7];
    // d_in[8] = mask (int32 tril) — causal, applied analytically.

    float* ws   = (float*)d_ws;
    float* vals = ws;                            // 2M floats (8 MB)
    float* outp = ws + XY;                       // 2M floats (8 MB)
    unsigned short* bfb = (unsigned short*)(ws + 2 * XY);
    unsigned short* xh  = bfb;
    unsigned short* xl  = bfb + XY;
    unsigned short* Wth = bfb + 2 * XY;
    unsigned short* Wtl = Wth + WT;
    unsigned short* Wph = Wtl + WT;
    unsigned short* Wpl = Wph + WP;
    unsigned short* qh  = Wpl + WP;
    unsigned short* ql  = qh + PL;
    unsigned short* kh  = ql + PL;
    unsigned short* kl  = kh + PL;
    unsigned short* vT  = kl + PL;
    // Reuse (dead regions during attention):
    //   Op: 2*512*64*64 bf16 = 4,194,304 ushorts == xh+xl region exactly.
    //   ml: 2*512*64*2 = 131,072 floats, placed in outp (rewritten later).
    unsigned short* Op = xh;
    float* ml = outp;

    const int attn_lds = 18432 * 2 + 256;        // 37,120 B
    hipFuncSetAttribute((const void*)attn,
                        hipFuncAttributeMaxDynamicSharedMemorySize, attn_lds);

    prep<<<dim3(1344), 256, 0, stream>>>(x, Wp, Wq, Wk, Wv,
                                         xh, xl, Wph, Wpl, Wth, Wtl);
    qkv_gemm<<<dim3(Mn / 128, 12), 256, 0, stream>>>(xh, xl, Wth, Wtl,
                                                     qh, ql, kh, kl, vT);
    attn<<<dim3(1024), 256, attn_lds, stream>>>(qh, ql, kh, kl, vT, Op, ml);
    attn_combine<<<dim3(512), 256, 0, stream>>>(Op, ml, vals);
    out_gemm<<<dim3(Mn / 64, En / 128), 256, 0, stream>>>(vals, Wph, Wpl, bp, x, outp);
    ln_kernel<<<dim3(Mn), 256, 0, stream>>>(outp, gamma, beta, (float*)d_out);
}

// Round 8
// 182.929 us; speedup vs baseline: 12.8482x; 1.0084x over previous
//
#include <hip/hip_runtime.h>

// Problem constants
constexpr int Bn = 2;
constexpr int Sn = 2048;
constexpr int En = 512;
constexpr int Hn = 8;
constexpr int Dn = 64;
constexpr int Mn = Bn * Sn;              // 4096 rows

typedef short bf8 __attribute__((ext_vector_type(8)));
typedef float f32x4 __attribute__((ext_vector_type(4)));

// element counts (ushort units) for the bf16 workspace region
constexpr size_t XY = (size_t)Mn * En;          // 2,097,152  x planes
constexpr size_t WT = (size_t)3 * En * En;      //   786,432  Wqkv transposed planes
constexpr size_t WP = (size_t)En * En;          //   262,144  Wp planes
constexpr size_t PL = (size_t)Bn * Hn * Sn * Dn;// 2,097,152  q/k/v planes

__device__ __forceinline__ unsigned short f2bf(float f) {
    unsigned int u = __float_as_uint(f);
    unsigned int r = 0x7FFFu + ((u >> 16) & 1u);
    return (unsigned short)((u + r) >> 16);
}
__device__ __forceinline__ float bf2f(unsigned short u) {
    return __uint_as_float(((unsigned int)u) << 16);
}
__device__ __forceinline__ void split2(float f, unsigned short& hi, unsigned short& lo) {
    hi = f2bf(f);
    lo = f2bf(f - bf2f(hi));
}

// ---------------------------------------------------------------------------
// Prep (fused): blocks [0,1024) presplit x; [1024,1152) presplit Wp;
// [1152,1344) transpose+split Wq/Wk/Wv -> Wt[n][k]. (unchanged from R7)
// ---------------------------------------------------------------------------
__global__ __launch_bounds__(256)
void prep(const float* __restrict__ x, const float* __restrict__ Wp,
          const float* __restrict__ Wq, const float* __restrict__ Wk,
          const float* __restrict__ Wv,
          unsigned short* __restrict__ xh, unsigned short* __restrict__ xl,
          unsigned short* __restrict__ Wph, unsigned short* __restrict__ Wpl,
          unsigned short* __restrict__ Wth, unsigned short* __restrict__ Wtl)
{
    __shared__ float t[64][65];
    const int bid = blockIdx.x;
    const int tid = threadIdx.x;

    if (bid < 1152) {
        const float* src = (bid < 1024) ? x : Wp;
        unsigned short* hp = (bid < 1024) ? xh : Wph;
        unsigned short* lp = (bid < 1024) ? xl : Wpl;
        const int blk = (bid < 1024) ? bid : (bid - 1024);
        const size_t base = ((size_t)blk * 256 + tid) * 8;
        float a[8];
        *(float4*)&a[0] = *(const float4*)(src + base);
        *(float4*)&a[4] = *(const float4*)(src + base + 4);
        unsigned short h[8], l[8];
        #pragma unroll
        for (int j = 0; j < 8; ++j) split2(a[j], h[j], l[j]);
        *(bf8*)(hp + base) = *(bf8*)&h[0];
        *(bf8*)(lp + base) = *(bf8*)&l[0];
        return;
    }

    const int idx = bid - 1152;           // 0..191
    const int ph = idx >> 3;              // 0..23
    const int proj = ph >> 3, h = ph & 7;
    const int e0 = (idx & 7) * 64;
    const float* W = (proj == 0) ? Wq : (proj == 1) ? Wk : Wv;
    const float* src = W + (size_t)h * En * Dn + (size_t)e0 * Dn;

    const int er = tid >> 2, cg = (tid & 3) * 16;
    #pragma unroll
    for (int c = 0; c < 4; ++c) {
        float4 v = *(const float4*)(src + (size_t)er * Dn + cg + 4 * c);
        t[er][cg + 4 * c + 0] = v.x;
        t[er][cg + 4 * c + 1] = v.y;
        t[er][cg + 4 * c + 2] = v.z;
        t[er][cg + 4 * c + 3] = v.w;
    }
    __syncthreads();

    const int d = tid >> 2, jg = (tid & 3) * 16;
    unsigned short h16[16], l16[16];
    #pragma unroll
    for (int j = 0; j < 16; ++j) split2(t[jg + j][d], h16[j], l16[j]);
    const size_t n = (size_t)proj * 512 + h * 64 + d;
    unsigned short* dh = Wth + n * En + e0 + jg;
    unsigned short* dl = Wtl + n * En + e0 + jg;
    *(bf8*)dh       = *(bf8*)&h16[0];
    *(bf8*)(dh + 8) = *(bf8*)&h16[8];
    *(bf8*)dl       = *(bf8*)&l16[0];
    *(bf8*)(dl + 8) = *(bf8*)&l16[8];
}

// ---------------------------------------------------------------------------
// Kernel 1 (v4): fused QKV projection. Main loop unchanged; q/k epilogue now
// routes acc through an LDS fp32 transpose (reusing the staging LDS) so the
// global writes are 16B bf8 stores instead of 128 scalar ushort stores.
// ---------------------------------------------------------------------------
__global__ __launch_bounds__(256)
void qkv_gemm(const unsigned short* __restrict__ xh,
              const unsigned short* __restrict__ xl,
              const unsigned short* __restrict__ Wth,
              const unsigned short* __restrict__ Wtl,
              unsigned short* __restrict__ qh_g,
              unsigned short* __restrict__ ql_g,
              unsigned short* __restrict__ kh_g,
              unsigned short* __restrict__ kl_g,
              unsigned short* __restrict__ vT_g)
{
    __shared__ __align__(16) unsigned char smraw[40960];
    unsigned short (*Ah)[40] = (unsigned short(*)[40])(smraw);
    unsigned short (*Al)[40] = (unsigned short(*)[40])(smraw + 10240);
    unsigned short (*Bh)[40] = (unsigned short(*)[40])(smraw + 20480);
    unsigned short (*Bl)[40] = (unsigned short(*)[40])(smraw + 30720);
    float (*Cf)[132] = (float(*)[132])(smraw);   // 64 x 132 fp32 = 33,792 B

    const int tid = threadIdx.x;
    const int m0 = blockIdx.x * 128;
    const int n0 = blockIdx.y * 128;
    const int proj = n0 >> 9;
    const int within = n0 & 511;

    const int wave = tid >> 6, lane = tid & 63;
    const int wm = (wave >> 1) * 64, wn = (wave & 1) * 64;
    const int lm = lane & 15, quad = lane >> 4;

    const int am = tid >> 1;
    const int aks = (tid & 1) * 16;
    const unsigned short* arh = xh + (size_t)(m0 + am) * En + aks;
    const unsigned short* arl = xl + (size_t)(m0 + am) * En + aks;

    const int nn = tid & 127;
    const int bkg = (tid >> 7) * 16;
    const unsigned short* brh = Wth + (size_t)(n0 + nn) * En + bkg;
    const unsigned short* brl = Wtl + (size_t)(n0 + nn) * En + bkg;

    f32x4 acc[4][4];
    #pragma unroll
    for (int i = 0; i < 4; ++i)
        #pragma unroll
        for (int j = 0; j < 4; ++j) acc[i][j] = (f32x4){0.f, 0.f, 0.f, 0.f};

    for (int k0 = 0; k0 < En; k0 += 32) {
        *(bf8*)&Ah[am][aks]     = *(const bf8*)(arh + k0);
        *(bf8*)&Ah[am][aks + 8] = *(const bf8*)(arh + k0 + 8);
        *(bf8*)&Al[am][aks]     = *(const bf8*)(arl + k0);
        *(bf8*)&Al[am][aks + 8] = *(const bf8*)(arl + k0 + 8);
        *(bf8*)&Bh[nn][bkg]     = *(const bf8*)(brh + k0);
        *(bf8*)&Bh[nn][bkg + 8] = *(const bf8*)(brh + k0 + 8);
        *(bf8*)&Bl[nn][bkg]     = *(const bf8*)(brl + k0);
        *(bf8*)&Bl[nn][bkg + 8] = *(const bf8*)(brl + k0 + 8);
        __syncthreads();

        bf8 a_h[4], a_l[4], b_h[4], b_l[4];
        #pragma unroll
        for (int mi = 0; mi < 4; ++mi) {
            a_h[mi] = *(const bf8*)&Ah[wm + mi * 16 + lm][quad * 8];
            a_l[mi] = *(const bf8*)&Al[wm + mi * 16 + lm][quad * 8];
        }
        #pragma unroll
        for (int ni = 0; ni < 4; ++ni) {
            b_h[ni] = *(const bf8*)&Bh[wn + ni * 16 + lm][quad * 8];
            b_l[ni] = *(const bf8*)&Bl[wn + ni * 16 + lm][quad * 8];
        }
        #pragma unroll
        for (int mi = 0; mi < 4; ++mi)
            #pragma unroll
            for (int ni = 0; ni < 4; ++ni) {
                acc[mi][ni] = __builtin_amdgcn_mfma_f32_16x16x32_bf16(a_h[mi], b_h[ni], acc[mi][ni], 0, 0, 0);
                acc[mi][ni] = __builtin_amdgcn_mfma_f32_16x16x32_bf16(a_h[mi], b_l[ni], acc[mi][ni], 0, 0, 0);
                acc[mi][ni] = __builtin_amdgcn_mfma_f32_16x16x32_bf16(a_l[mi], b_h[ni], acc[mi][ni], 0, 0, 0);
            }
        __syncthreads();
    }

    if (proj < 2) {
        unsigned short* hp = (proj == 0) ? qh_g : kh_g;
        unsigned short* lp = (proj == 0) ? ql_g : kl_g;
        // two passes over mi-pairs through the LDS fp32 transpose buffer
        #pragma unroll
        for (int p = 0; p < 2; ++p) {
            #pragma unroll
            for (int dmi = 0; dmi < 2; ++dmi) {
                const int mi = 2 * p + dmi;
                #pragma unroll
                for (int ni = 0; ni < 4; ++ni)
                    #pragma unroll
                    for (int r = 0; r < 4; ++r)
                        Cf[(wave >> 1) * 32 + dmi * 16 + quad * 4 + r]
                          [wn + ni * 16 + lm] = acc[mi][ni][r];
            }
            __syncthreads();
            {
                const int lr = tid & 63;
                const int cg = (tid >> 6) * 32;     // wave-uniform
                const int m = m0 + 64 * (lr >> 5) + 32 * p + 16 * ((lr >> 4) & 1) + (lr & 15);
                const int b = m >> 11, s = m & 2047;
                const int ng = within + cg;
                const int h = ng >> 6, d = ng & 63; // 32-chunk stays in one head
                unsigned short hi[32], lo[32];
                #pragma unroll
                for (int j4 = 0; j4 < 8; ++j4) {
                    float4 v = *(const float4*)&Cf[lr][cg + 4 * j4];
                    split2(v.x, hi[4 * j4 + 0], lo[4 * j4 + 0]);
                    split2(v.y, hi[4 * j4 + 1], lo[4 * j4 + 1]);
                    split2(v.z, hi[4 * j4 + 2], lo[4 * j4 + 2]);
                    split2(v.w, hi[4 * j4 + 3], lo[4 * j4 + 3]);
                }
                const size_t base = (((size_t)(b * Hn + h) * Sn + s) * Dn) + d;
                #pragma unroll
                for (int c = 0; c < 4; ++c) {
                    *(bf8*)(hp + base + 8 * c) = *(bf8*)&hi[8 * c];
                    *(bf8*)(lp + base + 8 * c) = *(bf8*)&lo[8 * c];
                }
            }
            __syncthreads();
        }
    } else {
        #pragma unroll
        for (int mi = 0; mi < 4; ++mi) {
            const int s0 = m0 + wm + mi * 16 + quad * 4;
            const int b = s0 >> 11, s = s0 & 2047;
            #pragma unroll
            for (int ni = 0; ni < 4; ++ni) {
                const int nl = within + wn + ni * 16 + lm;
                const int h = nl >> 6, d = nl & 63;
                ushort4 pk;
                pk.x = f2bf(acc[mi][ni][0]);
                pk.y = f2bf(acc[mi][ni][1]);
                pk.z = f2bf(acc[mi][ni][2]);
                pk.w = f2bf(acc[mi][ni][3]);
                *(ushort4*)(vT_g + ((size_t)(b * Hn + h) * Dn + d) * Sn + s) = pk;
            }
        }
    }
}

// ---------------------------------------------------------------------------
// Kernel 2 (v5): MFMA flash attention, split-t (unchanged from R7).
// ---------------------------------------------------------------------------
__global__ __launch_bounds__(256)
void attn(const unsigned short* __restrict__ qh_g,
          const unsigned short* __restrict__ ql_g,
          const unsigned short* __restrict__ kh_g,
          const unsigned short* __restrict__ kl_g,
          const unsigned short* __restrict__ vT_g,
          unsigned short* __restrict__ Op,
          float* __restrict__ ml)
{
    extern __shared__ unsigned short sm[];
    unsigned short (*khs)[72] = (unsigned short(*)[72])(sm);          // [t][d] hi
    unsigned short (*kls)[72] = (unsigned short(*)[72])(sm + 4608);   // [t][d] lo
    unsigned short (*vTs)[72] = (unsigned short(*)[72])(sm + 9216);   // [d][t]
    unsigned short (*pts)[72] = (unsigned short(*)[72])(sm + 13824);  // [q][t]
    float* alf = (float*)(sm + 18432);                                // [64]

    const int bidx = blockIdx.x;
    const int r_ = bidx & 255, quarter = bidx >> 8;
    const int a_ = r_ >> 4, bh = r_ & 15;
    const int qt = (quarter & 1) ? (31 - a_) : a_;
    const int hf = quarter >> 1;
    const int n0 = (qt + 2) >> 1;
    const int its = hf ? n0 : 0;
    const int ite = hf ? (qt + 1) : n0;
    const int pslot = hf * 512 + bh * 32 + qt;

    const int tid = threadIdx.x;
    const int wave = tid >> 6, lane = tid & 63;
    const int quad = lane >> 4, lq = lane & 15;

    const unsigned short* khb = kh_g + (size_t)bh * Sn * Dn;
    const unsigned short* klb = kl_g + (size_t)bh * Sn * Dn;
    const unsigned short* vTb = vT_g + (size_t)bh * Dn * Sn;

    bf8 qfh[2], qfl[2];
    {
        const size_t qoff = ((size_t)bh * Sn + (size_t)qt * 64 + wave * 16 + lq) * Dn;
        #pragma unroll
        for (int c = 0; c < 2; ++c) {
            qfh[c] = *(const bf8*)(qh_g + qoff + c * 32 + quad * 8);
            qfl[c] = *(const bf8*)(ql_g + qoff + c * 32 + quad * 8);
        }
    }

    f32x4 accO[4];
    #pragma unroll
    for (int nj = 0; nj < 4; ++nj) accO[nj] = (f32x4){0.f, 0.f, 0.f, 0.f};
    float m = -1e30f, l = 0.f;

    const int srow = tid & 63;
    const int sdg  = tid >> 6;

    bf8 pk0, pk1, pl0, pl1, pv0, pv1;
    if (its < ite) {
        const int t0 = its * 64;
        const unsigned short* kr = khb + (size_t)(t0 + srow) * Dn + sdg * 16;
        const unsigned short* lr = klb + (size_t)(t0 + srow) * Dn + sdg * 16;
        const unsigned short* vr = vTb + (size_t)srow * Sn + t0 + sdg * 16;
        pk0 = *(const bf8*)(kr);  pk1 = *(const bf8*)(kr + 8);
        pl0 = *(const bf8*)(lr);  pl1 = *(const bf8*)(lr + 8);
        pv0 = *(const bf8*)(vr);  pv1 = *(const bf8*)(vr + 8);
    }

    for (int it = its; it < ite; ++it) {
        __syncthreads();
        *(bf8*)&khs[srow][sdg * 16]     = pk0;
        *(bf8*)&khs[srow][sdg * 16 + 8] = pk1;
        *(bf8*)&kls[srow][sdg * 16]     = pl0;
        *(bf8*)&kls[srow][sdg * 16 + 8] = pl1;
        *(bf8*)&vTs[srow][sdg * 16]     = pv0;
        *(bf8*)&vTs[srow][sdg * 16 + 8] = pv1;
        __syncthreads();

        if (it + 1 < ite) {
            const int t1 = (it + 1) * 64;
            const unsigned short* kr = khb + (size_t)(t1 + srow) * Dn + sdg * 16;
            const unsigned short* lr = klb + (size_t)(t1 + srow) * Dn + sdg * 16;
            const unsigned short* vr = vTb + (size_t)srow * Sn + t1 + sdg * 16;
            pk0 = *(const bf8*)(kr);  pk1 = *(const bf8*)(kr + 8);
            pl0 = *(const bf8*)(lr);  pl1 = *(const bf8*)(lr + 8);
            pv0 = *(const bf8*)(vr);  pv1 = *(const bf8*)(vr + 8);
        }

        f32x4 accS[4];
        #pragma unroll
        for (int mi = 0; mi < 4; ++mi) accS[mi] = (f32x4){0.f, 0.f, 0.f, 0.f};
        #pragma unroll
        for (int mi = 0; mi < 4; ++mi) {
            #pragma unroll
            for (int c = 0; c < 2; ++c) {
                bf8 ah = *(const bf8*)&khs[mi * 16 + lq][c * 32 + quad * 8];
                bf8 al = *(const bf8*)&kls[mi * 16 + lq][c * 32 + quad * 8];
                accS[mi] = __builtin_amdgcn_mfma_f32_16x16x32_bf16(ah, qfh[c], accS[mi], 0, 0, 0);
                accS[mi] = __builtin_amdgcn_mfma_f32_16x16x32_bf16(ah, qfl[c], accS[mi], 0, 0, 0);
                accS[mi] = __builtin_amdgcn_mfma_f32_16x16x32_bf16(al, qfh[c], accS[mi], 0, 0, 0);
            }
        }

        if (it == qt) {
            const int qrel = wave * 16 + lq;
            #pragma unroll
            for (int mi = 0; mi < 4; ++mi)
                #pragma unroll
                for (int r = 0; r < 4; ++r)
                    if (mi * 16 + quad * 4 + r > qrel) accS[mi][r] = -INFINITY;
        }

        float mt = -INFINITY;
        #pragma unroll
        for (int mi = 0; mi < 4; ++mi)
            #pragma unroll
            for (int r = 0; r < 4; ++r) mt = fmaxf(mt, accS[mi][r]);
        mt = fmaxf(mt, __shfl_xor(mt, 16));
        mt = fmaxf(mt, __shfl_xor(mt, 32));
        const float mnew = fmaxf(m, mt);
        const float alpha = __expf(m - mnew);
        float ls = 0.f;
        #pragma unroll
        for (int mi = 0; mi < 4; ++mi)
            #pragma unroll
            for (int r = 0; r < 4; ++r) {
                const float p = __expf(accS[mi][r] - mnew);
                accS[mi][r] = p;
                ls += p;
            }
        ls += __shfl_xor(ls, 16);
        ls += __shfl_xor(ls, 32);
        l = l * alpha + ls;
        m = mnew;

        #pragma unroll
        for (int mi = 0; mi < 4; ++mi) {
            ushort4 pk;
            pk.x = f2bf(accS[mi][0]);
            pk.y = f2bf(accS[mi][1]);
            pk.z = f2bf(accS[mi][2]);
            pk.w = f2bf(accS[mi][3]);
            *(ushort4*)&pts[wave * 16 + lq][mi * 16 + quad * 4] = pk;
        }
        if (quad == 0) alf[wave * 16 + lq] = alpha;

        {
            float4 al4 = *(const float4*)&alf[wave * 16 + quad * 4];
            #pragma unroll
            for (int nj = 0; nj < 4; ++nj) {
                accO[nj][0] *= al4.x;
                accO[nj][1] *= al4.y;
                accO[nj][2] *= al4.z;
                accO[nj][3] *= al4.w;
            }
            #pragma unroll
            for (int c = 0; c < 2; ++c) {
                bf8 pf = *(const bf8*)&pts[wave * 16 + lq][c * 32 + quad * 8];
                #pragma unroll
                for (int nj = 0; nj < 4; ++nj) {
                    bf8 vf = *(const bf8*)&vTs[nj * 16 + lq][c * 32 + quad * 8];
                    accO[nj] = __builtin_amdgcn_mfma_f32_16x16x32_bf16(pf, vf, accO[nj], 0, 0, 0);
                }
            }
        }
    }

    if (quad == 0) {
        const size_t mi_ = ((size_t)pslot * 64 + wave * 16 + lq) * 2;
        ml[mi_]     = m;
        ml[mi_ + 1] = l;
    }
    #pragma unroll
    for (int r = 0; r < 4; ++r) {
        const int q = wave * 16 + quad * 4 + r;
        unsigned short* dst = Op + ((size_t)pslot * 64 + q) * 64;
        #pragma unroll
        for (int nj = 0; nj < 4; ++nj)
            dst[nj * 16 + lq] = f2bf(accO[nj][r]);
    }
}

// ---------------------------------------------------------------------------
// Kernel 3 (v4): fused combine + out-projection + residual.
// A[m][e] = sum over two split-t halves of Op, combined with per-(row,head)
// scales from ml, head-reversed (h = 7 - e/64). Then C = A Wp^T + bp + x.
// ---------------------------------------------------------------------------
__global__ __launch_bounds__(256)
void out_gemm(const unsigned short* __restrict__ Op,
              const float* __restrict__ ml,
              const unsigned short* __restrict__ Wph,
              const unsigned short* __restrict__ Wpl,
              const float* __restrict__ bp,
              const float* __restrict__ x,
              float* __restrict__ outp)
{
    __shared__ unsigned short Ah[64][40], Al[64][40];
    __shared__ unsigned short Bh[128][40], Bl[128][40];

    const int tid = threadIdx.x;
    const int m0 = blockIdx.x * 64;
    const int n0 = blockIdx.y * 128;

    const int wave = tid >> 6, lane = tid & 63;
    const int wm = (wave >> 1) * 32, wn = (wave & 1) * 64;
    const int lm = lane & 15, quad = lane >> 4;

    // A staging: thread owns row am, k-chunk of 8
    const int am = tid >> 2;
    const int aks = (tid & 3) * 8;
    const int m_row = m0 + am;
    const int b_row = m_row >> 11, s_row = m_row & 2047;
    const int qt = s_row >> 6, qq = s_row & 63;

    // per-head combine scales c0/c1 for this row
    float c0[8], c1[8];
    #pragma unroll
    for (int h = 0; h < 8; ++h) {
        const size_t base0 = (((size_t)(b_row * 8 + h) * 32 + qt) * 64 + qq) * 2;
        const size_t base1 = base0 + (size_t)512 * 64 * 2;
        const float m0_ = ml[base0], l0_ = ml[base0 + 1];
        const float m1_ = ml[base1], l1_ = ml[base1 + 1];
        const float mn = fmaxf(m0_, m1_);
        const float a0 = __expf(m0_ - mn), a1 = __expf(m1_ - mn);
        const float inv = 1.f / (a0 * l0_ + a1 * l1_);
        c0[h] = a0 * inv;
        c1[h] = a1 * inv;
    }

    const int bn = tid >> 1;
    const int bks = (tid & 1) * 16;
    const unsigned short* brh = Wph + (size_t)(n0 + bn) * En + bks;
    const unsigned short* brl = Wpl + (size_t)(n0 + bn) * En + bks;

    f32x4 acc[2][4];
    #pragma unroll
    for (int i = 0; i < 2; ++i)
        #pragma unroll
        for (int j = 0; j < 4; ++j) acc[i][j] = (f32x4){0.f, 0.f, 0.f, 0.f};

    for (int k0 = 0; k0 < En; k0 += 32) {
        {
            const int e0 = k0 + aks;          // 8 elems, single head
            const int h = 7 - (e0 >> 6);
            const int d = e0 & 63;
            const size_t p0 = (((size_t)(b_row * 8 + h) * 32 + qt) * 64 + qq) * 64 + d;
            const size_t p1 = p0 + (size_t)512 * 64 * 64;
            bf8 o0 = *(const bf8*)(Op + p0);
            bf8 o1 = *(const bf8*)(Op + p1);
            const float w0 = c0[h], w1 = c1[h];
            unsigned short hi[8], lo[8];
            #pragma unroll
            for (int j = 0; j < 8; ++j) {
                const float v = w0 * bf2f((unsigned short)o0[j]) +
                                w1 * bf2f((unsigned short)o1[j]);
                split2(v, hi[j], lo[j]);
            }
            *(bf8*)&Ah[am][aks] = *(bf8*)&hi[0];
            *(bf8*)&Al[am][aks] = *(bf8*)&lo[0];
        }
        *(bf8*)&Bh[bn][bks]     = *(const bf8*)(brh + k0);
        *(bf8*)&Bh[bn][bks + 8] = *(const bf8*)(brh + k0 + 8);
        *(bf8*)&Bl[bn][bks]     = *(const bf8*)(brl + k0);
        *(bf8*)&Bl[bn][bks + 8] = *(const bf8*)(brl + k0 + 8);
        __syncthreads();

        bf8 a_h[2], a_l[2], b_h[4], b_l[4];
        #pragma unroll
        for (int mi = 0; mi < 2; ++mi) {
            a_h[mi] = *(const bf8*)&Ah[wm + mi * 16 + lm][quad * 8];
            a_l[mi] = *(const bf8*)&Al[wm + mi * 16 + lm][quad * 8];
        }
        #pragma unroll
        for (int ni = 0; ni < 4; ++ni) {
            b_h[ni] = *(const bf8*)&Bh[wn + ni * 16 + lm][quad * 8];
            b_l[ni] = *(const bf8*)&Bl[wn + ni * 16 + lm][quad * 8];
        }
        #pragma unroll
        for (int mi = 0; mi < 2; ++mi)
            #pragma unroll
            for (int ni = 0; ni < 4; ++ni) {
                acc[mi][ni] = __builtin_amdgcn_mfma_f32_16x16x32_bf16(a_h[mi], b_h[ni], acc[mi][ni], 0, 0, 0);
                acc[mi][ni] = __builtin_amdgcn_mfma_f32_16x16x32_bf16(a_h[mi], b_l[ni], acc[mi][ni], 0, 0, 0);
                acc[mi][ni] = __builtin_amdgcn_mfma_f32_16x16x32_bf16(a_l[mi], b_h[ni], acc[mi][ni], 0, 0, 0);
            }
        __syncthreads();
    }

    #pragma unroll
    for (int mi = 0; mi < 2; ++mi) {
        #pragma unroll
        for (int r = 0; r < 4; ++r) {
            const int m = m0 + wm + mi * 16 + quad * 4 + r;
            #pragma unroll
            for (int ni = 0; ni < 4; ++ni) {
                const int n = n0 + wn + ni * 16 + lm;
                const size_t idx = (size_t)m * En + n;
                outp[idx] = acc[mi][ni][r] + bp[n] + x[idx];
            }
        }
    }
}

// ---------------------------------------------------------------------------
// Kernel 4 (v2): LayerNorm, 1 wave per row, shuffle-only (no LDS/barriers).
// 1024 blocks x 256 threads = 4 rows/block.
// ---------------------------------------------------------------------------
__global__ __launch_bounds__(256)
void ln_kernel(const float* __restrict__ outp,
               const float* __restrict__ gamma,
               const float* __restrict__ beta,
               float* __restrict__ y)
{
    const int row = blockIdx.x * 4 + (threadIdx.x >> 6);
    const int lane = threadIdx.x & 63;
    const float* r = outp + (size_t)row * En + lane * 8;

    float a[8];
    *(float4*)&a[0] = *(const float4*)(r);
    *(float4*)&a[4] = *(const float4*)(r + 4);

    float sum = 0.f, sq = 0.f;
    #pragma unroll
    for (int j = 0; j < 8; ++j) { sum += a[j]; sq += a[j] * a[j]; }
    #pragma unroll
    for (int off = 1; off < 64; off <<= 1) {
        sum += __shfl_xor(sum, off);
        sq  += __shfl_xor(sq, off);
    }
    const float mu = sum * (1.f / 512.f);
    const float var = sq * (1.f / 512.f) - mu * mu;
    const float rs = rsqrtf(var + 1e-5f);

    const float* g = gamma + lane * 8;
    const float* be = beta + lane * 8;
    float o[8];
    #pragma unroll
    for (int j = 0; j < 8; ++j)
        o[j] = (a[j] - mu) * rs * g[j] + be[j];
    float* yr = y + (size_t)row * En + lane * 8;
    *(float4*)(yr)     = *(float4*)&o[0];
    *(float4*)(yr + 4) = *(float4*)&o[4];
}

// ---------------------------------------------------------------------------
extern "C" void kernel_launch(void* const* d_in, const int* in_sizes, int n_in,
                              void* d_out, int out_size, void* d_ws, size_t ws_size,
                              hipStream_t stream)
{
    const float* x     = (const float*)d_in[0];
    const float* Wq    = (const float*)d_in[1];
    const float* Wk    = (const float*)d_in[2];
    const float* Wv    = (const float*)d_in[3];
    const float* Wp    = (const float*)d_in[4];
    const float* bp    = (const float*)d_in[5];
    const float* gamma = (const float*)d_in[6];
    const float* beta  = (const float*)d_in[7];
    // d_in[8] = mask (int32 tril) — causal, applied analytically.

    float* ws   = (float*)d_ws;
    float* ml   = ws;                            // 131,072 floats (old vals slot)
    float* outp = ws + XY;                       // 2M floats (8 MB)
    unsigned short* bfb = (unsigned short*)(ws + 2 * XY);
    unsigned short* xh  = bfb;
    unsigned short* xl  = bfb + XY;
    unsigned short* Wth = bfb + 2 * XY;
    unsigned short* Wtl = Wth + WT;
    unsigned short* Wph = Wtl + WT;
    unsigned short* Wpl = Wph + WP;
    unsigned short* qh  = Wpl + WP;
    unsigned short* ql  = qh + PL;
    unsigned short* kh  = ql + PL;
    unsigned short* kl  = kh + PL;
    unsigned short* vT  = kl + PL;
    // Op reuses xh+xl (dead after qkv_gemm): 2*512*64*64 = 4,194,304 ushorts.
    unsigned short* Op = xh;

    const int attn_lds = 18432 * 2 + 256;        // 37,120 B
    hipFuncSetAttribute((const void*)attn,
                        hipFuncAttributeMaxDynamicSharedMemorySize, attn_lds);

    prep<<<dim3(1344), 256, 0, stream>>>(x, Wp, Wq, Wk, Wv,
                                         xh, xl, Wph, Wpl, Wth, Wtl);
    qkv_gemm<<<dim3(Mn / 128, 12), 256, 0, stream>>>(xh, xl, Wth, Wtl,
                                                     qh, ql, kh, kl, vT);
    attn<<<dim3(1024), 256, attn_lds, stream>>>(qh, ql, kh, kl, vT, Op, ml);
    out_gemm<<<dim3(Mn / 64, En / 128), 256, 0, stream>>>(Op, ml, Wph, Wpl, bp, x, outp);
    ln_kernel<<<dim3(Mn / 4), 256, 0, stream>>>(outp, gamma, beta, (float*)d_out);
}

// Round 9
// 178.393 us; speedup vs baseline: 13.1750x; 1.0254x over previous
//
#include <hip/hip_runtime.h>

// Problem constants
constexpr int Bn = 2;
constexpr int Sn = 2048;
constexpr int En = 512;
constexpr int Hn = 8;
constexpr int Dn = 64;
constexpr int Mn = Bn * Sn;              // 4096 rows

typedef short bf8 __attribute__((ext_vector_type(8)));
typedef float f32x4 __attribute__((ext_vector_type(4)));

// element counts (ushort units) for the bf16 workspace region
constexpr size_t XY = (size_t)Mn * En;          // 2,097,152  x planes
constexpr size_t WT = (size_t)3 * En * En;      //   786,432  Wqkv transposed planes
constexpr size_t WP = (size_t)En * En;          //   262,144  Wp planes
constexpr size_t PL = (size_t)Bn * Hn * Sn * Dn;// 2,097,152  q/k/v planes

__device__ __forceinline__ unsigned short f2bf(float f) {
    unsigned int u = __float_as_uint(f);
    unsigned int r = 0x7FFFu + ((u >> 16) & 1u);
    return (unsigned short)((u + r) >> 16);
}
__device__ __forceinline__ float bf2f(unsigned short u) {
    return __uint_as_float(((unsigned int)u) << 16);
}
__device__ __forceinline__ void split2(float f, unsigned short& hi, unsigned short& lo) {
    hi = f2bf(f);
    lo = f2bf(f - bf2f(hi));
}

// ---------------------------------------------------------------------------
// Prep (fused): blocks [0,1024) presplit x; [1024,1152) presplit Wp;
// [1152,1344) transpose+split Wq/Wk/Wv -> Wt[n][k]. (unchanged)
// ---------------------------------------------------------------------------
__global__ __launch_bounds__(256)
void prep(const float* __restrict__ x, const float* __restrict__ Wp,
          const float* __restrict__ Wq, const float* __restrict__ Wk,
          const float* __restrict__ Wv,
          unsigned short* __restrict__ xh, unsigned short* __restrict__ xl,
          unsigned short* __restrict__ Wph, unsigned short* __restrict__ Wpl,
          unsigned short* __restrict__ Wth, unsigned short* __restrict__ Wtl)
{
    __shared__ float t[64][65];
    const int bid = blockIdx.x;
    const int tid = threadIdx.x;

    if (bid < 1152) {
        const float* src = (bid < 1024) ? x : Wp;
        unsigned short* hp = (bid < 1024) ? xh : Wph;
        unsigned short* lp = (bid < 1024) ? xl : Wpl;
        const int blk = (bid < 1024) ? bid : (bid - 1024);
        const size_t base = ((size_t)blk * 256 + tid) * 8;
        float a[8];
        *(float4*)&a[0] = *(const float4*)(src + base);
        *(float4*)&a[4] = *(const float4*)(src + base + 4);
        unsigned short h[8], l[8];
        #pragma unroll
        for (int j = 0; j < 8; ++j) split2(a[j], h[j], l[j]);
        *(bf8*)(hp + base) = *(bf8*)&h[0];
        *(bf8*)(lp + base) = *(bf8*)&l[0];
        return;
    }

    const int idx = bid - 1152;           // 0..191
    const int ph = idx >> 3;              // 0..23
    const int proj = ph >> 3, h = ph & 7;
    const int e0 = (idx & 7) * 64;
    const float* W = (proj == 0) ? Wq : (proj == 1) ? Wk : Wv;
    const float* src = W + (size_t)h * En * Dn + (size_t)e0 * Dn;

    const int er = tid >> 2, cg = (tid & 3) * 16;
    #pragma unroll
    for (int c = 0; c < 4; ++c) {
        float4 v = *(const float4*)(src + (size_t)er * Dn + cg + 4 * c);
        t[er][cg + 4 * c + 0] = v.x;
        t[er][cg + 4 * c + 1] = v.y;
        t[er][cg + 4 * c + 2] = v.z;
        t[er][cg + 4 * c + 3] = v.w;
    }
    __syncthreads();

    const int d = tid >> 2, jg = (tid & 3) * 16;
    unsigned short h16[16], l16[16];
    #pragma unroll
    for (int j = 0; j < 16; ++j) split2(t[jg + j][d], h16[j], l16[j]);
    const size_t n = (size_t)proj * 512 + h * 64 + d;
    unsigned short* dh = Wth + n * En + e0 + jg;
    unsigned short* dl = Wtl + n * En + e0 + jg;
    *(bf8*)dh       = *(bf8*)&h16[0];
    *(bf8*)(dh + 8) = *(bf8*)&h16[8];
    *(bf8*)dl       = *(bf8*)&l16[0];
    *(bf8*)(dl + 8) = *(bf8*)&l16[8];
}

// ---------------------------------------------------------------------------
// Kernel 1 (v5): fused QKV projection, 128x64 tiles (one head per block).
// Grid (32, 24) = 768 blocks -> exactly 3 blocks/CU (vs 384 @ 1.5 before).
// 4 waves of 64x32 (acc[4][2]). LDS 30,720 B.
// ---------------------------------------------------------------------------
__global__ __launch_bounds__(256)
void qkv_gemm(const unsigned short* __restrict__ xh,
              const unsigned short* __restrict__ xl,
              const unsigned short* __restrict__ Wth,
              const unsigned short* __restrict__ Wtl,
              unsigned short* __restrict__ qh_g,
              unsigned short* __restrict__ ql_g,
              unsigned short* __restrict__ kh_g,
              unsigned short* __restrict__ kl_g,
              unsigned short* __restrict__ vT_g)
{
    __shared__ __align__(16) unsigned char smraw[30720];
    unsigned short (*Ah)[40] = (unsigned short(*)[40])(smraw);          // 128 x 40
    unsigned short (*Al)[40] = (unsigned short(*)[40])(smraw + 10240);
    unsigned short (*Bh)[40] = (unsigned short(*)[40])(smraw + 20480);  // 64 x 40
    unsigned short (*Bl)[40] = (unsigned short(*)[40])(smraw + 25600);
    float (*Cf)[68] = (float(*)[68])(smraw);    // 64 x 68 fp32 = 17,408 B

    const int tid = threadIdx.x;
    const int m0 = blockIdx.x * 128;
    const int ny = blockIdx.y;            // 0..23
    const int proj = ny >> 3, h = ny & 7;

    const int wave = tid >> 6, lane = tid & 63;
    const int wm = (wave >> 1) * 64, wn = (wave & 1) * 32;
    const int lm = lane & 15, quad = lane >> 4;

    const int am = tid >> 1;              // 0..127
    const int aks = (tid & 1) * 16;
    const unsigned short* arh = xh + (size_t)(m0 + am) * En + aks;
    const unsigned short* arl = xl + (size_t)(m0 + am) * En + aks;

    const int bn = tid >> 2;              // 0..63
    const int bks = (tid & 3) * 8;
    const unsigned short* brh = Wth + (size_t)(ny * 64 + bn) * En + bks;
    const unsigned short* brl = Wtl + (size_t)(ny * 64 + bn) * En + bks;

    f32x4 acc[4][2];
    #pragma unroll
    for (int i = 0; i < 4; ++i)
        #pragma unroll
        for (int j = 0; j < 2; ++j) acc[i][j] = (f32x4){0.f, 0.f, 0.f, 0.f};

    for (int k0 = 0; k0 < En; k0 += 32) {
        *(bf8*)&Ah[am][aks]     = *(const bf8*)(arh + k0);
        *(bf8*)&Ah[am][aks + 8] = *(const bf8*)(arh + k0 + 8);
        *(bf8*)&Al[am][aks]     = *(const bf8*)(arl + k0);
        *(bf8*)&Al[am][aks + 8] = *(const bf8*)(arl + k0 + 8);
        *(bf8*)&Bh[bn][bks]     = *(const bf8*)(brh + k0);
        *(bf8*)&Bl[bn][bks]     = *(const bf8*)(brl + k0);
        __syncthreads();

        bf8 a_h[4], a_l[4], b_h[2], b_l[2];
        #pragma unroll
        for (int mi = 0; mi < 4; ++mi) {
            a_h[mi] = *(const bf8*)&Ah[wm + mi * 16 + lm][quad * 8];
            a_l[mi] = *(const bf8*)&Al[wm + mi * 16 + lm][quad * 8];
        }
        #pragma unroll
        for (int ni = 0; ni < 2; ++ni) {
            b_h[ni] = *(const bf8*)&Bh[wn + ni * 16 + lm][quad * 8];
            b_l[ni] = *(const bf8*)&Bl[wn + ni * 16 + lm][quad * 8];
        }
        #pragma unroll
        for (int mi = 0; mi < 4; ++mi)
            #pragma unroll
            for (int ni = 0; ni < 2; ++ni) {
                acc[mi][ni] = __builtin_amdgcn_mfma_f32_16x16x32_bf16(a_h[mi], b_h[ni], acc[mi][ni], 0, 0, 0);
                acc[mi][ni] = __builtin_amdgcn_mfma_f32_16x16x32_bf16(a_h[mi], b_l[ni], acc[mi][ni], 0, 0, 0);
                acc[mi][ni] = __builtin_amdgcn_mfma_f32_16x16x32_bf16(a_l[mi], b_h[ni], acc[mi][ni], 0, 0, 0);
            }
        __syncthreads();
    }

    if (proj < 2) {
        unsigned short* hp = (proj == 0) ? qh_g : kh_g;
        unsigned short* lp = (proj == 0) ? ql_g : kl_g;
        // two passes through the 64x68 fp32 transpose buffer (one wm group each)
        #pragma unroll
        for (int p = 0; p < 2; ++p) {
            if ((wave >> 1) == p) {
                #pragma unroll
                for (int mi = 0; mi < 4; ++mi)
                    #pragma unroll
                    for (int ni = 0; ni < 2; ++ni)
                        #pragma unroll
                        for (int r = 0; r < 4; ++r)
                            Cf[mi * 16 + quad * 4 + r][wn + ni * 16 + lm] = acc[mi][ni][r];
            }
            __syncthreads();
            {
                const int lr = tid & 63;
                const int cg = (tid >> 6) * 16;   // wave-uniform d-chunk
                const int m = m0 + p * 64 + lr;
                const int b = m >> 11, s = m & 2047;
                unsigned short hi[16], lo[16];
                #pragma unroll
                for (int j4 = 0; j4 < 4; ++j4) {
                    float4 v = *(const float4*)&Cf[lr][cg + 4 * j4];
                    split2(v.x, hi[4 * j4 + 0], lo[4 * j4 + 0]);
                    split2(v.y, hi[4 * j4 + 1], lo[4 * j4 + 1]);
                    split2(v.z, hi[4 * j4 + 2], lo[4 * j4 + 2]);
                    split2(v.w, hi[4 * j4 + 3], lo[4 * j4 + 3]);
                }
                const size_t base = (((size_t)(b * Hn + h) * Sn + s) * Dn) + cg;
                *(bf8*)(hp + base)     = *(bf8*)&hi[0];
                *(bf8*)(hp + base + 8) = *(bf8*)&hi[8];
                *(bf8*)(lp + base)     = *(bf8*)&lo[0];
                *(bf8*)(lp + base + 8) = *(bf8*)&lo[8];
            }
            __syncthreads();
        }
    } else {
        // V: transposed bf16 store, pack 4 consecutive s per ushort4
        #pragma unroll
        for (int mi = 0; mi < 4; ++mi) {
            const int s0 = m0 + wm + mi * 16 + quad * 4;
            const int b = s0 >> 11, s = s0 & 2047;
            #pragma unroll
            for (int ni = 0; ni < 2; ++ni) {
                const int d = wn + ni * 16 + lm;
                ushort4 pk;
                pk.x = f2bf(acc[mi][ni][0]);
                pk.y = f2bf(acc[mi][ni][1]);
                pk.z = f2bf(acc[mi][ni][2]);
                pk.w = f2bf(acc[mi][ni][3]);
                *(ushort4*)(vT_g + ((size_t)(b * Hn + h) * Dn + d) * Sn + s) = pk;
            }
        }
    }
}

// ---------------------------------------------------------------------------
// Kernel 2 (v5): MFMA flash attention, split-t (unchanged from R7/R8).
// ---------------------------------------------------------------------------
__global__ __launch_bounds__(256)
void attn(const unsigned short* __restrict__ qh_g,
          const unsigned short* __restrict__ ql_g,
          const unsigned short* __restrict__ kh_g,
          const unsigned short* __restrict__ kl_g,
          const unsigned short* __restrict__ vT_g,
          unsigned short* __restrict__ Op,
          float* __restrict__ ml)
{
    extern __shared__ unsigned short sm[];
    unsigned short (*khs)[72] = (unsigned short(*)[72])(sm);          // [t][d] hi
    unsigned short (*kls)[72] = (unsigned short(*)[72])(sm + 4608);   // [t][d] lo
    unsigned short (*vTs)[72] = (unsigned short(*)[72])(sm + 9216);   // [d][t]
    unsigned short (*pts)[72] = (unsigned short(*)[72])(sm + 13824);  // [q][t]
    float* alf = (float*)(sm + 18432);                                // [64]

    const int bidx = blockIdx.x;
    const int r_ = bidx & 255, quarter = bidx >> 8;
    const int a_ = r_ >> 4, bh = r_ & 15;
    const int qt = (quarter & 1) ? (31 - a_) : a_;
    const int hf = quarter >> 1;
    const int n0 = (qt + 2) >> 1;
    const int its = hf ? n0 : 0;
    const int ite = hf ? (qt + 1) : n0;
    const int pslot = hf * 512 + bh * 32 + qt;

    const int tid = threadIdx.x;
    const int wave = tid >> 6, lane = tid & 63;
    const int quad = lane >> 4, lq = lane & 15;

    const unsigned short* khb = kh_g + (size_t)bh * Sn * Dn;
    const unsigned short* klb = kl_g + (size_t)bh * Sn * Dn;
    const unsigned short* vTb = vT_g + (size_t)bh * Dn * Sn;

    bf8 qfh[2], qfl[2];
    {
        const size_t qoff = ((size_t)bh * Sn + (size_t)qt * 64 + wave * 16 + lq) * Dn;
        #pragma unroll
        for (int c = 0; c < 2; ++c) {
            qfh[c] = *(const bf8*)(qh_g + qoff + c * 32 + quad * 8);
            qfl[c] = *(const bf8*)(ql_g + qoff + c * 32 + quad * 8);
        }
    }

    f32x4 accO[4];
    #pragma unroll
    for (int nj = 0; nj < 4; ++nj) accO[nj] = (f32x4){0.f, 0.f, 0.f, 0.f};
    float m = -1e30f, l = 0.f;

    const int srow = tid & 63;
    const int sdg  = tid >> 6;

    bf8 pk0, pk1, pl0, pl1, pv0, pv1;
    if (its < ite) {
        const int t0 = its * 64;
        const unsigned short* kr = khb + (size_t)(t0 + srow) * Dn + sdg * 16;
        const unsigned short* lr = klb + (size_t)(t0 + srow) * Dn + sdg * 16;
        const unsigned short* vr = vTb + (size_t)srow * Sn + t0 + sdg * 16;
        pk0 = *(const bf8*)(kr);  pk1 = *(const bf8*)(kr + 8);
        pl0 = *(const bf8*)(lr);  pl1 = *(const bf8*)(lr + 8);
        pv0 = *(const bf8*)(vr);  pv1 = *(const bf8*)(vr + 8);
    }

    for (int it = its; it < ite; ++it) {
        __syncthreads();
        *(bf8*)&khs[srow][sdg * 16]     = pk0;
        *(bf8*)&khs[srow][sdg * 16 + 8] = pk1;
        *(bf8*)&kls[srow][sdg * 16]     = pl0;
        *(bf8*)&kls[srow][sdg * 16 + 8] = pl1;
        *(bf8*)&vTs[srow][sdg * 16]     = pv0;
        *(bf8*)&vTs[srow][sdg * 16 + 8] = pv1;
        __syncthreads();

        if (it + 1 < ite) {
            const int t1 = (it + 1) * 64;
            const unsigned short* kr = khb + (size_t)(t1 + srow) * Dn + sdg * 16;
            const unsigned short* lr = klb + (size_t)(t1 + srow) * Dn + sdg * 16;
            const unsigned short* vr = vTb + (size_t)srow * Sn + t1 + sdg * 16;
            pk0 = *(const bf8*)(kr);  pk1 = *(const bf8*)(kr + 8);
            pl0 = *(const bf8*)(lr);  pl1 = *(const bf8*)(lr + 8);
            pv0 = *(const bf8*)(vr);  pv1 = *(const bf8*)(vr + 8);
        }

        f32x4 accS[4];
        #pragma unroll
        for (int mi = 0; mi < 4; ++mi) accS[mi] = (f32x4){0.f, 0.f, 0.f, 0.f};
        #pragma unroll
        for (int mi = 0; mi < 4; ++mi) {
            #pragma unroll
            for (int c = 0; c < 2; ++c) {
                bf8 ah = *(const bf8*)&khs[mi * 16 + lq][c * 32 + quad * 8];
                bf8 al = *(const bf8*)&kls[mi * 16 + lq][c * 32 + quad * 8];
                accS[mi] = __builtin_amdgcn_mfma_f32_16x16x32_bf16(ah, qfh[c], accS[mi], 0, 0, 0);
                accS[mi] = __builtin_amdgcn_mfma_f32_16x16x32_bf16(ah, qfl[c], accS[mi], 0, 0, 0);
                accS[mi] = __builtin_amdgcn_mfma_f32_16x16x32_bf16(al, qfh[c], accS[mi], 0, 0, 0);
            }
        }

        if (it == qt) {
            const int qrel = wave * 16 + lq;
            #pragma unroll
            for (int mi = 0; mi < 4; ++mi)
                #pragma unroll
                for (int r = 0; r < 4; ++r)
                    if (mi * 16 + quad * 4 + r > qrel) accS[mi][r] = -INFINITY;
        }

        float mt = -INFINITY;
        #pragma unroll
        for (int mi = 0; mi < 4; ++mi)
            #pragma unroll
            for (int r = 0; r < 4; ++r) mt = fmaxf(mt, accS[mi][r]);
        mt = fmaxf(mt, __shfl_xor(mt, 16));
        mt = fmaxf(mt, __shfl_xor(mt, 32));
        const float mnew = fmaxf(m, mt);
        const float alpha = __expf(m - mnew);
        float ls = 0.f;
        #pragma unroll
        for (int mi = 0; mi < 4; ++mi)
            #pragma unroll
            for (int r = 0; r < 4; ++r) {
                const float p = __expf(accS[mi][r] - mnew);
                accS[mi][r] = p;
                ls += p;
            }
        ls += __shfl_xor(ls, 16);
        ls += __shfl_xor(ls, 32);
        l = l * alpha + ls;
        m = mnew;

        #pragma unroll
        for (int mi = 0; mi < 4; ++mi) {
            ushort4 pk;
            pk.x = f2bf(accS[mi][0]);
            pk.y = f2bf(accS[mi][1]);
            pk.z = f2bf(accS[mi][2]);
            pk.w = f2bf(accS[mi][3]);
            *(ushort4*)&pts[wave * 16 + lq][mi * 16 + quad * 4] = pk;
        }
        if (quad == 0) alf[wave * 16 + lq] = alpha;

        {
            float4 al4 = *(const float4*)&alf[wave * 16 + quad * 4];
            #pragma unroll
            for (int nj = 0; nj < 4; ++nj) {
                accO[nj][0] *= al4.x;
                accO[nj][1] *= al4.y;
                accO[nj][2] *= al4.z;
                accO[nj][3] *= al4.w;
            }
            #pragma unroll
            for (int c = 0; c < 2; ++c) {
                bf8 pf = *(const bf8*)&pts[wave * 16 + lq][c * 32 + quad * 8];
                #pragma unroll
                for (int nj = 0; nj < 4; ++nj) {
                    bf8 vf = *(const bf8*)&vTs[nj * 16 + lq][c * 32 + quad * 8];
                    accO[nj] = __builtin_amdgcn_mfma_f32_16x16x32_bf16(pf, vf, accO[nj], 0, 0, 0);
                }
            }
        }
    }

    if (quad == 0) {
        const size_t mi_ = ((size_t)pslot * 64 + wave * 16 + lq) * 2;
        ml[mi_]     = m;
        ml[mi_ + 1] = l;
    }
    #pragma unroll
    for (int r = 0; r < 4; ++r) {
        const int q = wave * 16 + quad * 4 + r;
        unsigned short* dst = Op + ((size_t)pslot * 64 + q) * 64;
        #pragma unroll
        for (int nj = 0; nj < 4; ++nj)
            dst[nj * 16 + lq] = f2bf(accO[nj][r]);
    }
}

// ---------------------------------------------------------------------------
// Kernel 3 (v5): fused combine + out-projection + residual, split-K=2.
// Grid (64, 4, 2) = 512 blocks (2/CU). kz=0 adds bias+residual -> outp;
// kz=1 writes raw partial -> outp2. ln sums them.
// ---------------------------------------------------------------------------
__global__ __launch_bounds__(256)
void out_gemm(const unsigned short* __restrict__ Op,
              const float* __restrict__ ml,
              const unsigned short* __restrict__ Wph,
              const unsigned short* __restrict__ Wpl,
              const float* __restrict__ bp,
              const float* __restrict__ x,
              float* __restrict__ outp,
              float* __restrict__ outp2)
{
    __shared__ unsigned short Ah[64][40], Al[64][40];
    __shared__ unsigned short Bh[128][40], Bl[128][40];

    const int tid = threadIdx.x;
    const int m0 = blockIdx.x * 64;
    const int n0 = blockIdx.y * 128;
    const int kz = blockIdx.z;
    const int kbeg = kz * 256, kend = kbeg + 256;

    const int wave = tid >> 6, lane = tid & 63;
    const int wm = (wave >> 1) * 32, wn = (wave & 1) * 64;
    const int lm = lane & 15, quad = lane >> 4;

    const int am = tid >> 2;
    const int aks = (tid & 3) * 8;
    const int m_row = m0 + am;
    const int b_row = m_row >> 11, s_row = m_row & 2047;
    const int qt = s_row >> 6, qq = s_row & 63;

    // per-head combine scales c0/c1 for this row
    float c0[8], c1[8];
    #pragma unroll
    for (int h = 0; h < 8; ++h) {
        const size_t base0 = (((size_t)(b_row * 8 + h) * 32 + qt) * 64 + qq) * 2;
        const size_t base1 = base0 + (size_t)512 * 64 * 2;
        const float m0_ = ml[base0], l0_ = ml[base0 + 1];
        const float m1_ = ml[base1], l1_ = ml[base1 + 1];
        const float mn = fmaxf(m0_, m1_);
        const float a0 = __expf(m0_ - mn), a1 = __expf(m1_ - mn);
        const float inv = 1.f / (a0 * l0_ + a1 * l1_);
        c0[h] = a0 * inv;
        c1[h] = a1 * inv;
    }

    const int bn = tid >> 1;
    const int bks = (tid & 1) * 16;
    const unsigned short* brh = Wph + (size_t)(n0 + bn) * En + bks;
    const unsigned short* brl = Wpl + (size_t)(n0 + bn) * En + bks;

    f32x4 acc[2][4];
    #pragma unroll
    for (int i = 0; i < 2; ++i)
        #pragma unroll
        for (int j = 0; j < 4; ++j) acc[i][j] = (f32x4){0.f, 0.f, 0.f, 0.f};

    for (int k0 = kbeg; k0 < kend; k0 += 32) {
        {
            const int e0 = k0 + aks;          // 8 elems, single head
            const int h = 7 - (e0 >> 6);
            const int d = e0 & 63;
            const size_t p0 = (((size_t)(b_row * 8 + h) * 32 + qt) * 64 + qq) * 64 + d;
            const size_t p1 = p0 + (size_t)512 * 64 * 64;
            bf8 o0 = *(const bf8*)(Op + p0);
            bf8 o1 = *(const bf8*)(Op + p1);
            const float w0 = c0[h], w1 = c1[h];
            unsigned short hi[8], lo[8];
            #pragma unroll
            for (int j = 0; j < 8; ++j) {
                const float v = w0 * bf2f((unsigned short)o0[j]) +
                                w1 * bf2f((unsigned short)o1[j]);
                split2(v, hi[j], lo[j]);
            }
            *(bf8*)&Ah[am][aks] = *(bf8*)&hi[0];
            *(bf8*)&Al[am][aks] = *(bf8*)&lo[0];
        }
        *(bf8*)&Bh[bn][bks]     = *(const bf8*)(brh + k0);
        *(bf8*)&Bh[bn][bks + 8] = *(const bf8*)(brh + k0 + 8);
        *(bf8*)&Bl[bn][bks]     = *(const bf8*)(brl + k0);
        *(bf8*)&Bl[bn][bks + 8] = *(const bf8*)(brl + k0 + 8);
        __syncthreads();

        bf8 a_h[2], a_l[2], b_h[4], b_l[4];
        #pragma unroll
        for (int mi = 0; mi < 2; ++mi) {
            a_h[mi] = *(const bf8*)&Ah[wm + mi * 16 + lm][quad * 8];
            a_l[mi] = *(const bf8*)&Al[wm + mi * 16 + lm][quad * 8];
        }
        #pragma unroll
        for (int ni = 0; ni < 4; ++ni) {
            b_h[ni] = *(const bf8*)&Bh[wn + ni * 16 + lm][quad * 8];
            b_l[ni] = *(const bf8*)&Bl[wn + ni * 16 + lm][quad * 8];
        }
        #pragma unroll
        for (int mi = 0; mi < 2; ++mi)
            #pragma unroll
            for (int ni = 0; ni < 4; ++ni) {
                acc[mi][ni] = __builtin_amdgcn_mfma_f32_16x16x32_bf16(a_h[mi], b_h[ni], acc[mi][ni], 0, 0, 0);
                acc[mi][ni] = __builtin_amdgcn_mfma_f32_16x16x32_bf16(a_h[mi], b_l[ni], acc[mi][ni], 0, 0, 0);
                acc[mi][ni] = __builtin_amdgcn_mfma_f32_16x16x32_bf16(a_l[mi], b_h[ni], acc[mi][ni], 0, 0, 0);
            }
        __syncthreads();
    }

    float* dst = kz ? outp2 : outp;
    #pragma unroll
    for (int mi = 0; mi < 2; ++mi) {
        #pragma unroll
        for (int r = 0; r < 4; ++r) {
            const int m = m0 + wm + mi * 16 + quad * 4 + r;
            #pragma unroll
            for (int ni = 0; ni < 4; ++ni) {
                const int n = n0 + wn + ni * 16 + lm;
                const size_t idx = (size_t)m * En + n;
                const float extra = kz ? 0.f : (bp[n] + x[idx]);
                dst[idx] = acc[mi][ni][r] + extra;
            }
        }
    }
}

// ---------------------------------------------------------------------------
// Kernel 4 (v3): LayerNorm over (outp + outp2), 1 wave per row, shuffle-only.
// ---------------------------------------------------------------------------
__global__ __launch_bounds__(256)
void ln_kernel(const float* __restrict__ outp,
               const float* __restrict__ outp2,
               const float* __restrict__ gamma,
               const float* __restrict__ beta,
               float* __restrict__ y)
{
    const int row = blockIdx.x * 4 + (threadIdx.x >> 6);
    const int lane = threadIdx.x & 63;
    const size_t off = (size_t)row * En + lane * 8;

    float a[8], b2[8];
    *(float4*)&a[0] = *(const float4*)(outp + off);
    *(float4*)&a[4] = *(const float4*)(outp + off + 4);
    *(float4*)&b2[0] = *(const float4*)(outp2 + off);
    *(float4*)&b2[4] = *(const float4*)(outp2 + off + 4);
    #pragma unroll
    for (int j = 0; j < 8; ++j) a[j] += b2[j];

    float sum = 0.f, sq = 0.f;
    #pragma unroll
    for (int j = 0; j < 8; ++j) { sum += a[j]; sq += a[j] * a[j]; }
    #pragma unroll
    for (int off_ = 1; off_ < 64; off_ <<= 1) {
        sum += __shfl_xor(sum, off_);
        sq  += __shfl_xor(sq, off_);
    }
    const float mu = sum * (1.f / 512.f);
    const float var = sq * (1.f / 512.f) - mu * mu;
    const float rs = rsqrtf(var + 1e-5f);

    const float* g = gamma + lane * 8;
    const float* be = beta + lane * 8;
    float o[8];
    #pragma unroll
    for (int j = 0; j < 8; ++j)
        o[j] = (a[j] - mu) * rs * g[j] + be[j];
    float* yr = y + off;
    *(float4*)(yr)     = *(float4*)&o[0];
    *(float4*)(yr + 4) = *(float4*)&o[4];
}

// ---------------------------------------------------------------------------
extern "C" void kernel_launch(void* const* d_in, const int* in_sizes, int n_in,
                              void* d_out, int out_size, void* d_ws, size_t ws_size,
                              hipStream_t stream)
{
    const float* x     = (const float*)d_in[0];
    const float* Wq    = (const float*)d_in[1];
    const float* Wk    = (const float*)d_in[2];
    const float* Wv    = (const float*)d_in[3];
    const float* Wp    = (const float*)d_in[4];
    const float* bp    = (const float*)d_in[5];
    const float* gamma = (const float*)d_in[6];
    const float* beta  = (const float*)d_in[7];
    // d_in[8] = mask (int32 tril) — causal, applied analytically.

    float* ws   = (float*)d_ws;
    float* ml   = ws;                            // 131,072 floats
    float* outp = ws + XY;                       // 2M floats (8 MB)
    unsigned short* bfb = (unsigned short*)(ws + 2 * XY);
    unsigned short* xh  = bfb;
    unsigned short* xl  = bfb + XY;
    unsigned short* Wth = bfb + 2 * XY;
    unsigned short* Wtl = Wth + WT;
    unsigned short* Wph = Wtl + WT;
    unsigned short* Wpl = Wph + WP;
    unsigned short* qh  = Wpl + WP;
    unsigned short* ql  = qh + PL;
    unsigned short* kh  = ql + PL;
    unsigned short* kl  = kh + PL;
    unsigned short* vT  = kl + PL;
    // Reuse of dead regions:
    //   Op reuses xh+xl (dead after qkv_gemm): 4,194,304 ushorts.
    //   outp2 reuses qh.. (dead after attn): needs 8 MB <= 21 MB available.
    unsigned short* Op = xh;
    float* outp2 = (float*)qh;

    const int attn_lds = 18432 * 2 + 256;        // 37,120 B
    hipFuncSetAttribute((const void*)attn,
                        hipFuncAttributeMaxDynamicSharedMemorySize, attn_lds);

    prep<<<dim3(1344), 256, 0, stream>>>(x, Wp, Wq, Wk, Wv,
                                         xh, xl, Wph, Wpl, Wth, Wtl);
    qkv_gemm<<<dim3(Mn / 128, 24), 256, 0, stream>>>(xh, xl, Wth, Wtl,
                                                     qh, ql, kh, kl, vT);
    attn<<<dim3(1024), 256, attn_lds, stream>>>(qh, ql, kh, kl, vT, Op, ml);
    out_gemm<<<dim3(Mn / 64, En / 128, 2), 256, 0, stream>>>(Op, ml, Wph, Wpl,
                                                             bp, x, outp, outp2);
    ln_kernel<<<dim3(Mn / 4), 256, 0, stream>>>(outp, outp2, gamma, beta,
                                                (float*)d_out);
}